// Round 2
// baseline (359.599 us; speedup 1.0000x reference)
//
#include <hip/hip_runtime.h>
#include <math.h>

#define D_MODEL 256
#define NHEAD   8
#define NLVL    4
#define NPTS    4
#define DHEAD   32
#define DFFN    1024
#define NQ      900
#define BSZ     4
#define NROW    (NQ * BSZ)      // 3600
#define S_TOT   11253
#define VROWS   (S_TOT * BSZ)   // 45012
#define SASCALE 0.17677669529663687f

typedef __attribute__((ext_vector_type(8))) short short8;
typedef __attribute__((ext_vector_type(4))) float f32x4;
typedef unsigned short ushort_t;

static __device__ __forceinline__ unsigned f2bf1(float f) {
    unsigned u = __float_as_uint(f);
    return (u + 0x7FFFu + ((u >> 16) & 1u)) >> 16;
}
static __device__ __forceinline__ unsigned pack2bf(float x, float y) {
    return f2bf1(x) | (f2bf1(y) << 16);
}
static __device__ __forceinline__ float bf2f(ushort_t u) {
    return __uint_as_float(((unsigned)u) << 16);
}

#define GPAD 72

// bf16 weight buffer element offsets
#define WB_IN   0         // 768*256
#define WB_VP   196608    // 256*256
#define WB_OUTP 262144    // 256*256
#define WB_OFF  327680    // 256*256
#define WB_AW   393216    // 128*256
#define WB_OP   425984    // 256*256
#define WB_L1   491520    // 1024*256
#define WB_L2   753664    // 256*1024
#define WB_TOT  1015808

// ---------------------------------------------------------------------------
// One-shot fp32 -> bf16 conversion of all weight matrices.
// ---------------------------------------------------------------------------
__global__ __launch_bounds__(256) void cvt_weights(
    const float* __restrict__ w_in, const float* __restrict__ w_vp,
    const float* __restrict__ w_outp, const float* __restrict__ w_off,
    const float* __restrict__ w_aw, const float* __restrict__ w_op,
    const float* __restrict__ w_l1, const float* __restrict__ w_l2,
    ushort_t* __restrict__ dst)
{
    int b = blockIdx.x;
    const float* src;
    int dstoff;
    if (b < 96)       { src = w_in;   dstoff = WB_IN;   }
    else if (b < 128) { src = w_vp;   b -= 96;  dstoff = WB_VP;   }
    else if (b < 160) { src = w_outp; b -= 128; dstoff = WB_OUTP; }
    else if (b < 192) { src = w_off;  b -= 160; dstoff = WB_OFF;  }
    else if (b < 208) { src = w_aw;   b -= 192; dstoff = WB_AW;   }
    else if (b < 240) { src = w_op;   b -= 208; dstoff = WB_OP;   }
    else if (b < 368) { src = w_l1;   b -= 240; dstoff = WB_L1;   }
    else              { src = w_l2;   b -= 368; dstoff = WB_L2;   }
    int i = (b * 256 + threadIdx.x) * 8;
    float4 f0 = *(const float4*)(src + i);
    float4 f1 = *(const float4*)(src + i + 4);
    uint4 u;
    u.x = pack2bf(f0.x, f0.y); u.y = pack2bf(f0.z, f0.w);
    u.z = pack2bf(f1.x, f1.y); u.w = pack2bf(f1.z, f1.w);
    *(uint4*)(dst + dstoff + i) = u;
}

// ---------------------------------------------------------------------------
// proj_fused: qkv projection (blocks 0..683) + value projection (684..2091).
// R12: vproj blocks now compute the FULL 256 output cols per 64-row tile.
// The 256-row W tile is staged in two sequential 128-row halves through the
// same 18.4 KB Ws buffer, so LDS stays 27.6 KB while the A tile is fetched
// from HBM exactly once (was twice with the N-split).
// ---------------------------------------------------------------------------
__global__ __launch_bounds__(256) void proj_fused(
    const float* __restrict__ tgt, const float* __restrict__ qpos,
    const ushort_t* __restrict__ in_wb, const float* __restrict__ in_b,
    const float* __restrict__ mem, const ushort_t* __restrict__ vp_wb,
    const float* __restrict__ vp_b,
    ushort_t* __restrict__ qkv16, ushort_t* __restrict__ value16)
{
    __shared__ ushort_t As[64 * GPAD];    // 9216 B
    __shared__ ushort_t Ws[128 * GPAD];   // 18432 B

    const int t    = threadIdx.x;
    const int bid  = blockIdx.x;
    const int trow = t >> 2;
    const int tk   = (t & 3) << 4;
    const int wv   = t >> 6;
    const int ln   = t & 63;
    const int L    = ln & 15;
    const int quad = ln >> 4;

    if (bid < 684) {
        // ---------------- QKV path (64x64 tiles) ----------------
        const int m0 = (bid % 57) * 64;
        const int n0 = (bid / 57) * 64;
        const bool addpos = (n0 < 512);
        const float oscale = (n0 < 256) ? SASCALE : 1.f;

        const int  mrow = m0 + trow;
        const bool mv   = (mrow < NROW);
        const float* arow = tgt  + (size_t)mrow * 256 + tk;
        const float* prow = qpos + (size_t)mrow * 256 + tk;
        const ushort_t* wrow = in_wb + (size_t)(n0 + trow) * 256 + tk;

        f32x4 acc[4] = {{0.f,0.f,0.f,0.f},{0.f,0.f,0.f,0.f},
                        {0.f,0.f,0.f,0.f},{0.f,0.f,0.f,0.f}};

        for (int k0 = 0; k0 < 256; k0 += 64) {
            uint4 u0, u1;
            if (mv) {
                const float* ap = arow + k0;
                float4 a0 = *(const float4*)(ap + 0);
                float4 a1 = *(const float4*)(ap + 4);
                float4 a2 = *(const float4*)(ap + 8);
                float4 a3 = *(const float4*)(ap + 12);
                if (addpos) {
                    const float* pp = prow + k0;
                    float4 p0 = *(const float4*)(pp + 0);
                    float4 p1 = *(const float4*)(pp + 4);
                    float4 p2 = *(const float4*)(pp + 8);
                    float4 p3 = *(const float4*)(pp + 12);
                    a0.x += p0.x; a0.y += p0.y; a0.z += p0.z; a0.w += p0.w;
                    a1.x += p1.x; a1.y += p1.y; a1.z += p1.z; a1.w += p1.w;
                    a2.x += p2.x; a2.y += p2.y; a2.z += p2.z; a2.w += p2.w;
                    a3.x += p3.x; a3.y += p3.y; a3.z += p3.z; a3.w += p3.w;
                }
                u0.x = pack2bf(a0.x, a0.y); u0.y = pack2bf(a0.z, a0.w);
                u0.z = pack2bf(a1.x, a1.y); u0.w = pack2bf(a1.z, a1.w);
                u1.x = pack2bf(a2.x, a2.y); u1.y = pack2bf(a2.z, a2.w);
                u1.z = pack2bf(a3.x, a3.y); u1.w = pack2bf(a3.z, a3.w);
            } else {
                u0 = make_uint4(0u, 0u, 0u, 0u); u1 = u0;
            }
            *(uint4*)&As[trow * GPAD + tk + 0] = u0;
            *(uint4*)&As[trow * GPAD + tk + 8] = u1;
            {
                const ushort_t* wp = wrow + k0;
                *(uint4*)&Ws[trow * GPAD + tk + 0] = *(const uint4*)(wp + 0);
                *(uint4*)&Ws[trow * GPAD + tk + 8] = *(const uint4*)(wp + 8);
            }
            __syncthreads();
#pragma unroll
            for (int kh = 0; kh < 2; ++kh) {
                short8 af = *(const short8*)&As[(wv * 16 + L) * GPAD + kh * 32 + quad * 8];
#pragma unroll
                for (int cb = 0; cb < 4; ++cb) {
                    short8 bf = *(const short8*)&Ws[(cb * 16 + L) * GPAD + kh * 32 + quad * 8];
                    acc[cb] = __builtin_amdgcn_mfma_f32_16x16x32_bf16(af, bf, acc[cb], 0, 0, 0);
                }
            }
            __syncthreads();
        }
#pragma unroll
        for (int cb = 0; cb < 4; ++cb) {
            int col = n0 + cb * 16 + L;
            float bv = in_b[col];
#pragma unroll
            for (int i = 0; i < 4; ++i) {
                int m = m0 + wv * 16 + quad * 4 + i;
                if (m < NROW)
                    qkv16[(size_t)m * 768 + col] = (ushort_t)f2bf1((acc[cb][i] + bv) * oscale);
            }
        }
    } else {
        // -------- value-projection: 64 rows x 256 cols, A fetched once -----
        const int vb = bid - 684;        // 0..703
        const int m0 = vb * 64;

        const int  mrow = m0 + trow;
        const bool mv   = (mrow < VROWS);
        const float* arow = mem + (size_t)mrow * 256 + tk;

        f32x4 acc[16];
#pragma unroll
        for (int i = 0; i < 16; ++i) acc[i] = (f32x4){0.f, 0.f, 0.f, 0.f};

        for (int k0 = 0; k0 < 256; k0 += 64) {
            // stage A tile (bf16-converted)
            uint4 u0, u1;
            if (mv) {
                const float* ap = arow + k0;
                float4 a0 = *(const float4*)(ap + 0);
                float4 a1 = *(const float4*)(ap + 4);
                float4 a2 = *(const float4*)(ap + 8);
                float4 a3 = *(const float4*)(ap + 12);
                u0.x = pack2bf(a0.x, a0.y); u0.y = pack2bf(a0.z, a0.w);
                u0.z = pack2bf(a1.x, a1.y); u0.w = pack2bf(a1.z, a1.w);
                u1.x = pack2bf(a2.x, a2.y); u1.y = pack2bf(a2.z, a2.w);
                u1.z = pack2bf(a3.x, a3.y); u1.w = pack2bf(a3.z, a3.w);
            } else {
                u0 = make_uint4(0u, 0u, 0u, 0u); u1 = u0;
            }
            *(uint4*)&As[trow * GPAD + tk + 0] = u0;
            *(uint4*)&As[trow * GPAD + tk + 8] = u1;
            // stage W rows 0..127
#pragma unroll
            for (int wg = 0; wg < 2; ++wg) {
                int n = wg * 64 + trow;
                const ushort_t* wp = vp_wb + (size_t)n * 256 + k0 + tk;
                *(uint4*)&Ws[n * GPAD + tk + 0] = *(const uint4*)(wp + 0);
                *(uint4*)&Ws[n * GPAD + tk + 8] = *(const uint4*)(wp + 8);
            }
            __syncthreads();
#pragma unroll
            for (int kh = 0; kh < 2; ++kh) {
                short8 af = *(const short8*)&As[(wv * 16 + L) * GPAD + kh * 32 + quad * 8];
#pragma unroll
                for (int cb = 0; cb < 8; ++cb) {
                    short8 bf = *(const short8*)&Ws[(cb * 16 + L) * GPAD + kh * 32 + quad * 8];
                    acc[cb] = __builtin_amdgcn_mfma_f32_16x16x32_bf16(af, bf, acc[cb], 0, 0, 0);
                }
            }
            __syncthreads();
            // stage W rows 128..255 (same Ws buffer)
#pragma unroll
            for (int wg = 0; wg < 2; ++wg) {
                int n = wg * 64 + trow;
                const ushort_t* wp = vp_wb + (size_t)(128 + n) * 256 + k0 + tk;
                *(uint4*)&Ws[n * GPAD + tk + 0] = *(const uint4*)(wp + 0);
                *(uint4*)&Ws[n * GPAD + tk + 8] = *(const uint4*)(wp + 8);
            }
            __syncthreads();
#pragma unroll
            for (int kh = 0; kh < 2; ++kh) {
                short8 af = *(const short8*)&As[(wv * 16 + L) * GPAD + kh * 32 + quad * 8];
#pragma unroll
                for (int cb = 0; cb < 8; ++cb) {
                    short8 bf = *(const short8*)&Ws[(cb * 16 + L) * GPAD + kh * 32 + quad * 8];
                    acc[8 + cb] = __builtin_amdgcn_mfma_f32_16x16x32_bf16(af, bf, acc[8 + cb], 0, 0, 0);
                }
            }
            __syncthreads();
        }

        // epilogue: bias + bf16, repack through LDS (two 128-col passes)
        ushort_t* Cs = Ws;   // 64 rows x 136 stride = 17408 B (fits 18432)
#pragma unroll
        for (int half = 0; half < 2; ++half) {
            if (half) __syncthreads();
#pragma unroll
            for (int cb = 0; cb < 8; ++cb) {
                int col = cb * 16 + L;
                float bv = vp_b[half * 128 + col];
#pragma unroll
                for (int i = 0; i < 4; ++i) {
                    int r = wv * 16 + quad * 4 + i;
                    Cs[r * 136 + col] = (ushort_t)f2bf1(acc[half * 8 + cb][i] + bv);
                }
            }
            __syncthreads();
            {
                int r  = t >> 2;
                int ch = (t & 3) * 32;
                int m  = m0 + r;
                if (m < VROWS) {
                    const ushort_t* src = &Cs[r * 136 + ch];
                    uint4* dst = (uint4*)(value16 + (size_t)m * 256 + half * 128 + ch);
#pragma unroll
                    for (int j = 0; j < 4; ++j)
                        dst[j] = *(const uint4*)(src + j * 8);
                }
            }
        }
    }
}

// ---------------------------------------------------------------------------
// MFMA flash self-attention, bf16 in / bf16 out (unchanged).
// ---------------------------------------------------------------------------
__global__ __launch_bounds__(256) void sa_flash16(
    const ushort_t* __restrict__ qkv, ushort_t* __restrict__ attn_out)
{
    __shared__ ushort_t Ks[2 * 2080];
    __shared__ ushort_t Vt[2 * 2304];
    __shared__ ushort_t Ps[4 * 1152];

    const int t    = threadIdx.x;
    const int q0   = blockIdx.x * 64;
    const int b    = blockIdx.y & 3;
    const int h    = blockIdx.y >> 2;
    const int wv   = t >> 6;
    const int ln   = t & 63;
    const int L    = ln & 15;
    const int quad = ln >> 4;

    union { uint4 u; short8 s; } qu;
    qu.u = make_uint4(0u, 0u, 0u, 0u);
    {
        int q = q0 + wv * 16 + L;
        if (q < NQ)
            qu.u = *(const uint4*)(qkv + ((size_t)q * 4 + b) * 768 + h * 32 + quad * 8);
    }
    const short8 qf = qu.s;

    float mrun = -1e30f, lrun = 0.f;
    f32x4 oacc[2] = {{0.f,0.f,0.f,0.f},{0.f,0.f,0.f,0.f}};

    const int skey = t >> 2;
    const int sdg  = t & 3;

    uint4 ku, vu;
    auto kv_load = [&](int k0) {
        int kg = k0 + skey;
        ku = make_uint4(0u, 0u, 0u, 0u);
        vu = make_uint4(0u, 0u, 0u, 0u);
        if (kg < NQ) {
            const ushort_t* base = qkv + ((size_t)kg * 4 + b) * 768 + 256 + h * 32 + sdg * 8;
            ku = *(const uint4*)base;
            vu = *(const uint4*)(base + 256);
        }
    };

    kv_load(0);
    int it = 0;
    for (int k0 = 0; k0 < NQ; k0 += 64, it ^= 1) {
        *(uint4*)&Ks[it * 2080 + sdg * 520 + skey * 8] = ku;
        {
            ushort_t* vp = &Vt[it * 2304 + sdg * 8 * 72 + skey];
            vp[0 * 72] = (ushort_t)(vu.x & 0xffffu);
            vp[1 * 72] = (ushort_t)(vu.x >> 16);
            vp[2 * 72] = (ushort_t)(vu.y & 0xffffu);
            vp[3 * 72] = (ushort_t)(vu.y >> 16);
            vp[4 * 72] = (ushort_t)(vu.z & 0xffffu);
            vp[5 * 72] = (ushort_t)(vu.z >> 16);
            vp[6 * 72] = (ushort_t)(vu.w & 0xffffu);
            vp[7 * 72] = (ushort_t)(vu.w >> 16);
        }
        __syncthreads();
        if (k0 + 64 < NQ) kv_load(k0 + 64);

        f32x4 sacc[4] = {{0.f,0.f,0.f,0.f},{0.f,0.f,0.f,0.f},
                         {0.f,0.f,0.f,0.f},{0.f,0.f,0.f,0.f}};
#pragma unroll
        for (int cb = 0; cb < 4; ++cb) {
            short8 kf = *(const short8*)&Ks[it * 2080 + quad * 520 + (cb * 16 + L) * 8];
            sacc[cb] = __builtin_amdgcn_mfma_f32_16x16x32_bf16(kf, qf, sacc[cb], 0, 0, 0);
        }
        if (k0 + 64 > NQ) {
#pragma unroll
            for (int cb = 0; cb < 4; ++cb)
#pragma unroll
                for (int i = 0; i < 4; ++i)
                    if (k0 + cb * 16 + quad * 4 + i >= NQ) sacc[cb][i] = -1e30f;
        }

        float ml = -1e30f;
#pragma unroll
        for (int cb = 0; cb < 4; ++cb)
#pragma unroll
            for (int i = 0; i < 4; ++i) ml = fmaxf(ml, sacc[cb][i]);
        ml = fmaxf(ml, __shfl_xor(ml, 16, 64));
        ml = fmaxf(ml, __shfl_xor(ml, 32, 64));
        float mnew  = fmaxf(mrun, ml);
        float alpha = __expf(mrun - mnew);
        float p[16];
        float rs = 0.f;
#pragma unroll
        for (int cb = 0; cb < 4; ++cb)
#pragma unroll
            for (int i = 0; i < 4; ++i) {
                float e = __expf(sacc[cb][i] - mnew);
                p[cb * 4 + i] = e;
                rs += e;
            }
        rs += __shfl_xor(rs, 16, 64);
        rs += __shfl_xor(rs, 32, 64);
        lrun = lrun * alpha + rs;
        mrun = mnew;

        {
            ushort_t* pw = &Ps[wv * 1152 + L * 72];
#pragma unroll
            for (int cb = 0; cb < 4; ++cb) {
                uint2 u;
                u.x = pack2bf(p[cb * 4 + 0], p[cb * 4 + 1]);
                u.y = pack2bf(p[cb * 4 + 2], p[cb * 4 + 3]);
                *(uint2*)&pw[cb * 16 + quad * 4] = u;
            }
        }
#pragma unroll
        for (int i = 0; i < 4; ++i) {
            float ai = __shfl(alpha, quad * 4 + i, 64);
            oacc[0][i] *= ai;
            oacc[1][i] *= ai;
        }
        __syncthreads();

#pragma unroll
        for (int ks = 0; ks < 2; ++ks) {
            short8 pf = *(const short8*)&Ps[wv * 1152 + L * 72 + ks * 32 + quad * 8];
#pragma unroll
            for (int db = 0; db < 2; ++db) {
                short8 vf = *(const short8*)&Vt[it * 2304 + (db * 16 + L) * 72 + ks * 32 + quad * 8];
                oacc[db] = __builtin_amdgcn_mfma_f32_16x16x32_bf16(pf, vf, oacc[db], 0, 0, 0);
            }
        }
    }

#pragma unroll
    for (int i = 0; i < 4; ++i) {
        float lq = __shfl(lrun, quad * 4 + i, 64);
        float li = 1.f / lq;
        int q = q0 + wv * 16 + quad * 4 + i;
        if (q < NQ) {
            ushort_t* op = attn_out + ((size_t)q * 4 + b) * 256 + h * 32 + L;
            op[0]  = (ushort_t)f2bf1(oacc[0][i] * li);
            op[16] = (ushort_t)f2bf1(oacc[1][i] * li);
        }
    }
}

// ---------------------------------------------------------------------------
// gemm_ln16 (R12): fused  C = LN(resid + A@W^T + bias)  for N = 256.
// 64 rows x 256 cols per block; for a fixed row all 256 cols live in the 16
// lanes of one quad (16 acc regs x 16 lanes), so LN stats reduce with 4
// shfl_xor steps in exact fp32 — no fp32 tmp round-trip, no LN kernel.
// Outputs: out (fp32) and optional out2 = bf16(out + pos).
// ---------------------------------------------------------------------------
__global__ __launch_bounds__(256) void gemm_ln16(
    const ushort_t* __restrict__ A, const ushort_t* __restrict__ W,
    const float* __restrict__ bias, const float* __restrict__ resid,
    const float* __restrict__ gam, const float* __restrict__ bet,
    float* __restrict__ out, const float* __restrict__ pos,
    ushort_t* __restrict__ out2, int M, int K)
{
    __shared__ ushort_t As[64 * GPAD];    //  9216 B
    __shared__ ushort_t Ws[256 * GPAD];   // 36864 B

    const int t  = threadIdx.x;
    const int m0 = blockIdx.x * 64;
    const int trow = t >> 2;
    const int tk   = (t & 3) << 4;
    const int wv   = t >> 6;
    const int ln   = t & 63;
    const int L    = ln & 15;
    const int quad = ln >> 4;

    const int  mrow = m0 + trow;
    const bool mv   = (mrow < M);
    const ushort_t* arow = A + (size_t)mrow * K + tk;

    f32x4 acc[16];
#pragma unroll
    for (int i = 0; i < 16; ++i) acc[i] = (f32x4){0.f, 0.f, 0.f, 0.f};

    for (int k0 = 0; k0 < K; k0 += 64) {
        {
            uint4 a0 = make_uint4(0u,0u,0u,0u), a1 = a0;
            if (mv) {
                a0 = *(const uint4*)(arow + k0);
                a1 = *(const uint4*)(arow + k0 + 8);
            }
            *(uint4*)&As[trow * GPAD + tk + 0] = a0;
            *(uint4*)&As[trow * GPAD + tk + 8] = a1;
        }
#pragma unroll
        for (int wg = 0; wg < 4; ++wg) {
            int n = wg * 64 + trow;
            const ushort_t* wp = W + (size_t)n * K + k0 + tk;
            *(uint4*)&Ws[n * GPAD + tk + 0] = *(const uint4*)(wp + 0);
            *(uint4*)&Ws[n * GPAD + tk + 8] = *(const uint4*)(wp + 8);
        }
        __syncthreads();
#pragma unroll
        for (int kh = 0; kh < 2; ++kh) {
            short8 af = *(const short8*)&As[(wv * 16 + L) * GPAD + kh * 32 + quad * 8];
#pragma unroll
            for (int cb = 0; cb < 16; ++cb) {
                short8 bf = *(const short8*)&Ws[(cb * 16 + L) * GPAD + kh * 32 + quad * 8];
                acc[cb] = __builtin_amdgcn_mfma_f32_16x16x32_bf16(af, bf, acc[cb], 0, 0, 0);
            }
        }
        __syncthreads();
    }

    // ---- fused LN epilogue ----
    float s[4]  = {0.f, 0.f, 0.f, 0.f};
    float s2[4] = {0.f, 0.f, 0.f, 0.f};
#pragma unroll
    for (int cb = 0; cb < 16; ++cb) {
        int col = cb * 16 + L;
        float bv = bias[col];
#pragma unroll
        for (int i = 0; i < 4; ++i) {
            int m = m0 + wv * 16 + quad * 4 + i;
            float r = (m < M) ? resid[(size_t)m * 256 + col] : 0.f;
            float xv = acc[cb][i] + bv + r;
            acc[cb][i] = xv;
            s[i]  += xv;
            s2[i] += xv * xv;
        }
    }
#pragma unroll
    for (int off = 1; off < 16; off <<= 1) {
#pragma unroll
        for (int i = 0; i < 4; ++i) {
            s[i]  += __shfl_xor(s[i],  off, 64);
            s2[i] += __shfl_xor(s2[i], off, 64);
        }
    }
    float mean[4], rstd[4];
#pragma unroll
    for (int i = 0; i < 4; ++i) {
        mean[i] = s[i] * (1.f / 256.f);
        float var = s2[i] * (1.f / 256.f) - mean[i] * mean[i];
        rstd[i] = rsqrtf(var + 1e-5f);
    }
#pragma unroll
    for (int cb = 0; cb < 16; ++cb) {
        int col = cb * 16 + L;
        float gv = gam[col];
        float bt = bet[col];
#pragma unroll
        for (int i = 0; i < 4; ++i) {
            int m = m0 + wv * 16 + quad * 4 + i;
            if (m < M) {
                float y = (acc[cb][i] - mean[i]) * rstd[i] * gv + bt;
                out[(size_t)m * 256 + col] = y;
                if (out2) {
                    float o2 = y + (pos ? pos[(size_t)m * 256 + col] : 0.f);
                    out2[(size_t)m * 256 + col] = (ushort_t)f2bf1(o2);
                }
            }
        }
    }
}

// ---------------------------------------------------------------------------
// Fused offset + attention-weight GEMM (bf16 weights).
// ---------------------------------------------------------------------------
__global__ __launch_bounds__(256) void offaw16(
    const ushort_t* __restrict__ A,
    const ushort_t* __restrict__ off_wb, const float* __restrict__ off_b,
    const ushort_t* __restrict__ aw_wb, const float* __restrict__ aw_b,
    float* __restrict__ off_raw, float* __restrict__ aw_raw)
{
    __shared__ ushort_t As[64 * GPAD];
    __shared__ ushort_t Ws[64 * GPAD];

    const int t  = threadIdx.x;
    const int m0 = blockIdx.x * 64;
    const int by = blockIdx.y;
    const bool isaw = (by >= 4);
    const int n0 = isaw ? (by - 4) * 64 : by * 64;
    const ushort_t* W = isaw ? aw_wb : off_wb;
    const float* bs = isaw ? aw_b : off_b;
    float* C = isaw ? aw_raw : off_raw;
    const int ldc = isaw ? 128 : 256;

    const int trow = t >> 2;
    const int tk   = (t & 3) << 4;
    const int wv   = t >> 6;
    const int ln   = t & 63;
    const int L    = ln & 15;
    const int quad = ln >> 4;

    const int  mrow = m0 + trow;
    const bool mv   = (mrow < NROW);
    const ushort_t* arow = A + (size_t)mrow * 256 + tk;
    const ushort_t* wrow = W + (size_t)(n0 + trow) * 256 + tk;

    f32x4 acc[4] = {{0.f,0.f,0.f,0.f},{0.f,0.f,0.f,0.f},
                    {0.f,0.f,0.f,0.f},{0.f,0.f,0.f,0.f}};

    for (int k0 = 0; k0 < 256; k0 += 64) {
        {
            uint4 a0 = make_uint4(0u,0u,0u,0u), a1 = a0;
            if (mv) {
                a0 = *(const uint4*)(arow + k0);
                a1 = *(const uint4*)(arow + k0 + 8);
            }
            *(uint4*)&As[trow * GPAD + tk + 0] = a0;
            *(uint4*)&As[trow * GPAD + tk + 8] = a1;
        }
        {
            const ushort_t* wp = wrow + k0;
            *(uint4*)&Ws[trow * GPAD + tk + 0] = *(const uint4*)(wp + 0);
            *(uint4*)&Ws[trow * GPAD + tk + 8] = *(const uint4*)(wp + 8);
        }
        __syncthreads();
#pragma unroll
        for (int kh = 0; kh < 2; ++kh) {
            short8 af = *(const short8*)&As[(wv * 16 + L) * GPAD + kh * 32 + quad * 8];
#pragma unroll
            for (int cb = 0; cb < 4; ++cb) {
                short8 bf = *(const short8*)&Ws[(cb * 16 + L) * GPAD + kh * 32 + quad * 8];
                acc[cb] = __builtin_amdgcn_mfma_f32_16x16x32_bf16(af, bf, acc[cb], 0, 0, 0);
            }
        }
        __syncthreads();
    }
#pragma unroll
    for (int cb = 0; cb < 4; ++cb) {
        int col = n0 + cb * 16 + L;
        float bv = bs[col];
#pragma unroll
        for (int i = 0; i < 4; ++i) {
            int m = m0 + wv * 16 + quad * 4 + i;
            if (m < NROW)
                C[(size_t)m * ldc + col] = acc[cb][i] + bv;
        }
    }
}

// ---------------------------------------------------------------------------
// Generic A-bf16, W-bf16 -> C-bf16 GEMM (FFN1 with ReLU).
// ---------------------------------------------------------------------------
__global__ __launch_bounds__(256) void gemm16_16(
    const ushort_t* __restrict__ A, const ushort_t* __restrict__ W,
    const float* __restrict__ bias, ushort_t* __restrict__ C,
    int M, int N, int K, int ldc, int relu)
{
    __shared__ ushort_t As[64 * GPAD];
    __shared__ ushort_t Ws[64 * GPAD];

    const int t  = threadIdx.x;
    const int m0 = blockIdx.x * 64;
    const int n0 = blockIdx.y * 64;
    const int trow = t >> 2;
    const int tk   = (t & 3) << 4;
    const int wv   = t >> 6;
    const int ln   = t & 63;
    const int L    = ln & 15;
    const int quad = ln >> 4;

    const int  mrow = m0 + trow;
    const bool mv   = (mrow < M);
    const ushort_t* arow = A + (size_t)mrow * K + tk;
    const ushort_t* wrow = W + (size_t)(n0 + trow) * K + tk;

    f32x4 acc[4] = {{0.f,0.f,0.f,0.f},{0.f,0.f,0.f,0.f},
                    {0.f,0.f,0.f,0.f},{0.f,0.f,0.f,0.f}};

    for (int k0 = 0; k0 < K; k0 += 64) {
        {
            uint4 a0 = make_uint4(0u,0u,0u,0u), a1 = a0;
            if (mv) {
                a0 = *(const uint4*)(arow + k0);
                a1 = *(const uint4*)(arow + k0 + 8);
            }
            *(uint4*)&As[trow * GPAD + tk + 0] = a0;
            *(uint4*)&As[trow * GPAD + tk + 8] = a1;
        }
        {
            const ushort_t* wp = wrow + k0;
            *(uint4*)&Ws[trow * GPAD + tk + 0] = *(const uint4*)(wp + 0);
            *(uint4*)&Ws[trow * GPAD + tk + 8] = *(const uint4*)(wp + 8);
        }
        __syncthreads();
#pragma unroll
        for (int kh = 0; kh < 2; ++kh) {
            short8 af = *(const short8*)&As[(wv * 16 + L) * GPAD + kh * 32 + quad * 8];
#pragma unroll
            for (int cb = 0; cb < 4; ++cb) {
                short8 bf = *(const short8*)&Ws[(cb * 16 + L) * GPAD + kh * 32 + quad * 8];
                acc[cb] = __builtin_amdgcn_mfma_f32_16x16x32_bf16(af, bf, acc[cb], 0, 0, 0);
            }
        }
        __syncthreads();
    }
#pragma unroll
    for (int cb = 0; cb < 4; ++cb) {
        int col = n0 + cb * 16 + L;
        float bv = bias[col];
#pragma unroll
        for (int i = 0; i < 4; ++i) {
            int m = m0 + wv * 16 + quad * 4 + i;
            if (m < M) {
                float o = acc[cb][i] + bv;
                if (relu) o = fmaxf(o, 0.f);
                C[(size_t)m * ldc + col] = (ushort_t)f2bf1(o);
            }
        }
    }
}

// ---------------------------------------------------------------------------
// Multi-scale deformable sampling (unchanged).
// ---------------------------------------------------------------------------
__global__ __launch_bounds__(256) void msdeform16(
    const float* __restrict__ off_raw, const float* __restrict__ aw_raw,
    const float* __restrict__ refp, const ushort_t* __restrict__ value,
    ushort_t* __restrict__ out)
{
    const int row = blockIdx.x;   // q*4+b
    const int b = row & 3;
    const int t = threadIdx.x;

    __shared__ float aw_s[8][17];
    __shared__ float px_s[8][16];
    __shared__ float py_s[8][16];

    const int Hs[4]  = {92, 46, 23, 12};
    const int Wd[4]  = {92, 46, 23, 12};
    const int S0_[4] = {0, 8464, 10580, 11109};

    if (t < 128) {
        int hh = t >> 4, lp = t & 15, l = lp >> 2;
        float ox = off_raw[(size_t)row * 256 + hh * 32 + lp * 2 + 0];
        float oy = off_raw[(size_t)row * 256 + hh * 32 + lp * 2 + 1];
        float rx = refp[((size_t)row * 4 + l) * 2 + 0];
        float ry = refp[((size_t)row * 4 + l) * 2 + 1];
        px_s[hh][lp] = rx * (float)Wd[l] + ox - 0.5f;
        py_s[hh][lp] = ry * (float)Hs[l] + oy - 0.5f;
    }
    if (t < 8) {
        int hh = t;
        float v[16];
        float m = -1e30f;
#pragma unroll
        for (int j = 0; j < 16; ++j) {
            v[j] = aw_raw[(size_t)row * 128 + hh * 16 + j];
            m = fmaxf(m, v[j]);
        }
        float ssum = 0.f;
#pragma unroll
        for (int j = 0; j < 16; ++j) { v[j] = __expf(v[j] - m); ssum += v[j]; }
        float inv = 1.f / ssum;
#pragma unroll
        for (int j = 0; j < 16; ++j) aw_s[hh][j] = v[j] * inv;
    }
    __syncthreads();

    const int h = t >> 5, d = t & 31;
    const ushort_t* vb = value + (size_t)b * 256 + h * 32 + d;
    float acc = 0.f;
#pragma unroll
    for (int l = 0; l < 4; ++l) {
        const int H = Hs[l], W = Wd[l], base = S0_[l];
#pragma unroll
        for (int p = 0; p < 4; ++p) {
            const int lp = l * 4 + p;
            float px = px_s[h][lp], py = py_s[h][lp];
            float x0f = floorf(px), y0f = floorf(py);
            int x0 = (int)x0f, y0 = (int)y0f;
            float wx = px - x0f, wy = py - y0f;
            float sv = 0.f;
#pragma unroll
            for (int dy = 0; dy < 2; ++dy) {
#pragma unroll
                for (int dx = 0; dx < 2; ++dx) {
                    int xi = x0 + dx, yi = y0 + dy;
                    float flag = (xi >= 0 && xi < W && yi >= 0 && yi < H) ? 1.f : 0.f;
                    int xc = xi < 0 ? 0 : (xi >= W ? W - 1 : xi);
                    int yc = yi < 0 ? 0 : (yi >= H ? H - 1 : yi);
                    float wgt = (dx ? wx : 1.f - wx) * (dy ? wy : 1.f - wy);
                    float gv = bf2f(vb[(size_t)(base + yc * W + xc) * 1024]);
                    sv = fmaf(wgt * flag, gv, sv);
                }
            }
            acc = fmaf(aw_s[h][lp], sv, acc);
        }
    }
    out[(size_t)row * 256 + h * 32 + d] = (ushort_t)f2bf1(acc);
}

// ---------------------------------------------------------------------------
extern "C" void kernel_launch(void* const* d_in, const int* in_sizes, int n_in,
                              void* d_out, int out_size, void* d_ws, size_t ws_size,
                              hipStream_t stream)
{
    const float* tgt    = (const float*)d_in[0];
    const float* qpos   = (const float*)d_in[1];
    const float* refp   = (const float*)d_in[2];
    const float* mem    = (const float*)d_in[3];
    const float* in_w   = (const float*)d_in[6];
    const float* in_b   = (const float*)d_in[7];
    const float* outp_w = (const float*)d_in[8];
    const float* outp_b = (const float*)d_in[9];
    const float* off_w  = (const float*)d_in[10];
    const float* off_b  = (const float*)d_in[11];
    const float* aw_w   = (const float*)d_in[12];
    const float* aw_b   = (const float*)d_in[13];
    const float* vp_w   = (const float*)d_in[14];
    const float* vp_b   = (const float*)d_in[15];
    const float* op_w   = (const float*)d_in[16];
    const float* op_b   = (const float*)d_in[17];
    const float* ln1g   = (const float*)d_in[18];
    const float* ln1b   = (const float*)d_in[19];
    const float* ln2g   = (const float*)d_in[20];
    const float* ln2b   = (const float*)d_in[21];
    const float* ln3g   = (const float*)d_in[22];
    const float* ln3b   = (const float*)d_in[23];
    const float* l1w    = (const float*)d_in[24];
    const float* l1b    = (const float*)d_in[25];
    const float* l2w    = (const float*)d_in[26];
    const float* l2b    = (const float*)d_in[27];
    float* out = (float*)d_out;
    float* ws  = (float*)d_ws;

    // workspace layout (float units)
    ushort_t* qkv16    = (ushort_t*)ws;                 // 691200 floats
    ushort_t* att16    = (ushort_t*)(ws + 691200);      // 230400
    float*    tgt_a    = ws + 1843200;                  // 921600
    ushort_t* xca16    = (ushort_t*)(ws + 2764800);     // 230400
    float*    off_raw  = ws + 2995200;                  // 921600
    float*    aw_raw   = ws + 3916800;                  // 460800
    ushort_t* att2_16  = (ushort_t*)(ws + 4377600);     // 230400
    float*    tgt_b    = ws + 4608000;                  // 921600
    ushort_t* tgtb16   = (ushort_t*)(ws + 5529600);     // 230400
    ushort_t* value16  = (ushort_t*)(ws + 5760000);     // 5761536
    ushort_t* hidden16 = (ushort_t*)(ws + 11521536);    // 1843200
    ushort_t* wb       = (ushort_t*)(ws + 13364736);    // 507904 (bf16 weights)

    const ushort_t* in_wb   = wb + WB_IN;
    const ushort_t* vp_wb   = wb + WB_VP;
    const ushort_t* outp_wb = wb + WB_OUTP;
    const ushort_t* off_wb  = wb + WB_OFF;
    const ushort_t* aw_wb   = wb + WB_AW;
    const ushort_t* op_wb   = wb + WB_OP;
    const ushort_t* l1_wb   = wb + WB_L1;
    const ushort_t* l2_wb   = wb + WB_L2;

    dim3 b256(256);

    // 0. one-shot weight conversion fp32 -> bf16
    hipLaunchKernelGGL(cvt_weights, dim3(496), b256, 0, stream,
                       in_w, vp_w, outp_w, off_w, aw_w, op_w, l1w, l2w, wb);
    // 1. qkv + value projection (vproj full-width: A fetched once)
    hipLaunchKernelGGL(proj_fused, dim3(1388), b256, 0, stream,
                       tgt, qpos, in_wb, in_b, mem, vp_wb, vp_b, qkv16, value16);
    // 2. flash self-attention
    hipLaunchKernelGGL(sa_flash16, dim3(15, 32), b256, 0, stream, qkv16, att16);
    // 3. out-proj + LN2 fused: tgt_a = LN(tgt + attn@W + b); xca16 = bf16(tgt_a + qpos)
    hipLaunchKernelGGL(gemm_ln16, dim3(57), b256, 0, stream,
                       att16, outp_wb, outp_b, tgt, ln2g, ln2b,
                       tgt_a, qpos, xca16, NROW, 256);
    // 4. fused sampling-offset + attention-weight GEMMs
    hipLaunchKernelGGL(offaw16, dim3(57, 6), b256, 0, stream,
                       xca16, off_wb, off_b, aw_wb, aw_b, off_raw, aw_raw);
    // 5. deformable sampling (bf16 out)
    hipLaunchKernelGGL(msdeform16, dim3(3600), b256, 0, stream,
                       off_raw, aw_raw, refp, value16, att2_16);
    // 6. oproj + LN1 fused: tgt_b = LN(tgt_a + ca@W + b); tgtb16 = bf16(tgt_b)
    hipLaunchKernelGGL(gemm_ln16, dim3(57), b256, 0, stream,
                       att2_16, op_wb, op_b, tgt_a, ln1g, ln1b,
                       tgt_b, (const float*)nullptr, tgtb16, NROW, 256);
    // 7. FFN1 + ReLU (bf16 out)
    hipLaunchKernelGGL(gemm16_16, dim3(57, 16), b256, 0, stream,
                       tgtb16, l1_wb, l1b, hidden16, NROW, 1024, 256, 1024, 1);
    // 8. FFN2 + LN3 fused -> d_out
    hipLaunchKernelGGL(gemm_ln16, dim3(57), b256, 0, stream,
                       hidden16, l2_wb, l2b, tgt_b, ln3g, ln3b,
                       out, (const float*)nullptr, (ushort_t*)nullptr, NROW, 1024);
}

// Round 3
// 276.230 us; speedup vs baseline: 1.3018x; 1.3018x over previous
//
#include <hip/hip_runtime.h>
#include <math.h>

#define D_MODEL 256
#define NHEAD   8
#define NLVL    4
#define NPTS    4
#define DHEAD   32
#define DFFN    1024
#define NQ      900
#define BSZ     4
#define NROW    (NQ * BSZ)      // 3600
#define S_TOT   11253
#define VROWS   (S_TOT * BSZ)   // 45012
#define SASCALE 0.17677669529663687f

typedef __attribute__((ext_vector_type(8))) short short8;
typedef __attribute__((ext_vector_type(4))) float f32x4;
typedef unsigned short ushort_t;

static __device__ __forceinline__ unsigned f2bf1(float f) {
    unsigned u = __float_as_uint(f);
    return (u + 0x7FFFu + ((u >> 16) & 1u)) >> 16;
}
static __device__ __forceinline__ unsigned pack2bf(float x, float y) {
    return f2bf1(x) | (f2bf1(y) << 16);
}
static __device__ __forceinline__ float bf2f(ushort_t u) {
    return __uint_as_float(((unsigned)u) << 16);
}

#define GPAD 72

// bf16 weight buffer element offsets
#define WB_IN   0         // 768*256
#define WB_VP   196608    // 256*256
#define WB_OUTP 262144    // 256*256
#define WB_OFF  327680    // 256*256
#define WB_AW   393216    // 128*256
#define WB_OP   425984    // 256*256
#define WB_L1   491520    // 1024*256
#define WB_L2   753664    // 256*1024
#define WB_TOT  1015808

// ---------------------------------------------------------------------------
// One-shot fp32 -> bf16 conversion of all weight matrices.
// ---------------------------------------------------------------------------
__global__ __launch_bounds__(256) void cvt_weights(
    const float* __restrict__ w_in, const float* __restrict__ w_vp,
    const float* __restrict__ w_outp, const float* __restrict__ w_off,
    const float* __restrict__ w_aw, const float* __restrict__ w_op,
    const float* __restrict__ w_l1, const float* __restrict__ w_l2,
    ushort_t* __restrict__ dst)
{
    int b = blockIdx.x;
    const float* src;
    int dstoff;
    if (b < 96)       { src = w_in;   dstoff = WB_IN;   }
    else if (b < 128) { src = w_vp;   b -= 96;  dstoff = WB_VP;   }
    else if (b < 160) { src = w_outp; b -= 128; dstoff = WB_OUTP; }
    else if (b < 192) { src = w_off;  b -= 160; dstoff = WB_OFF;  }
    else if (b < 208) { src = w_aw;   b -= 192; dstoff = WB_AW;   }
    else if (b < 240) { src = w_op;   b -= 208; dstoff = WB_OP;   }
    else if (b < 368) { src = w_l1;   b -= 240; dstoff = WB_L1;   }
    else              { src = w_l2;   b -= 368; dstoff = WB_L2;   }
    int i = (b * 256 + threadIdx.x) * 8;
    float4 f0 = *(const float4*)(src + i);
    float4 f1 = *(const float4*)(src + i + 4);
    uint4 u;
    u.x = pack2bf(f0.x, f0.y); u.y = pack2bf(f0.z, f0.w);
    u.z = pack2bf(f1.x, f1.y); u.w = pack2bf(f1.z, f1.w);
    *(uint4*)(dst + dstoff + i) = u;
}

// ---------------------------------------------------------------------------
// proj_fused: qkv projection (blocks 0..683) + value projection (684..1387).
// vproj blocks compute the FULL 256 output cols per 64-row tile; W staged in
// two sequential 128-row halves so the A tile is fetched from HBM once.
// ---------------------------------------------------------------------------
__global__ __launch_bounds__(256) void proj_fused(
    const float* __restrict__ tgt, const float* __restrict__ qpos,
    const ushort_t* __restrict__ in_wb, const float* __restrict__ in_b,
    const float* __restrict__ mem, const ushort_t* __restrict__ vp_wb,
    const float* __restrict__ vp_b,
    ushort_t* __restrict__ qkv16, ushort_t* __restrict__ value16)
{
    __shared__ ushort_t As[64 * GPAD];    // 9216 B
    __shared__ ushort_t Ws[128 * GPAD];   // 18432 B

    const int t    = threadIdx.x;
    const int bid  = blockIdx.x;
    const int trow = t >> 2;
    const int tk   = (t & 3) << 4;
    const int wv   = t >> 6;
    const int ln   = t & 63;
    const int L    = ln & 15;
    const int quad = ln >> 4;

    if (bid < 684) {
        // ---------------- QKV path (64x64 tiles) ----------------
        const int m0 = (bid % 57) * 64;
        const int n0 = (bid / 57) * 64;
        const bool addpos = (n0 < 512);
        const float oscale = (n0 < 256) ? SASCALE : 1.f;

        const int  mrow = m0 + trow;
        const bool mv   = (mrow < NROW);
        const float* arow = tgt  + (size_t)mrow * 256 + tk;
        const float* prow = qpos + (size_t)mrow * 256 + tk;
        const ushort_t* wrow = in_wb + (size_t)(n0 + trow) * 256 + tk;

        f32x4 acc[4] = {{0.f,0.f,0.f,0.f},{0.f,0.f,0.f,0.f},
                        {0.f,0.f,0.f,0.f},{0.f,0.f,0.f,0.f}};

        for (int k0 = 0; k0 < 256; k0 += 64) {
            uint4 u0, u1;
            if (mv) {
                const float* ap = arow + k0;
                float4 a0 = *(const float4*)(ap + 0);
                float4 a1 = *(const float4*)(ap + 4);
                float4 a2 = *(const float4*)(ap + 8);
                float4 a3 = *(const float4*)(ap + 12);
                if (addpos) {
                    const float* pp = prow + k0;
                    float4 p0 = *(const float4*)(pp + 0);
                    float4 p1 = *(const float4*)(pp + 4);
                    float4 p2 = *(const float4*)(pp + 8);
                    float4 p3 = *(const float4*)(pp + 12);
                    a0.x += p0.x; a0.y += p0.y; a0.z += p0.z; a0.w += p0.w;
                    a1.x += p1.x; a1.y += p1.y; a1.z += p1.z; a1.w += p1.w;
                    a2.x += p2.x; a2.y += p2.y; a2.z += p2.z; a2.w += p2.w;
                    a3.x += p3.x; a3.y += p3.y; a3.z += p3.z; a3.w += p3.w;
                }
                u0.x = pack2bf(a0.x, a0.y); u0.y = pack2bf(a0.z, a0.w);
                u0.z = pack2bf(a1.x, a1.y); u0.w = pack2bf(a1.z, a1.w);
                u1.x = pack2bf(a2.x, a2.y); u1.y = pack2bf(a2.z, a2.w);
                u1.z = pack2bf(a3.x, a3.y); u1.w = pack2bf(a3.z, a3.w);
            } else {
                u0 = make_uint4(0u, 0u, 0u, 0u); u1 = u0;
            }
            *(uint4*)&As[trow * GPAD + tk + 0] = u0;
            *(uint4*)&As[trow * GPAD + tk + 8] = u1;
            {
                const ushort_t* wp = wrow + k0;
                *(uint4*)&Ws[trow * GPAD + tk + 0] = *(const uint4*)(wp + 0);
                *(uint4*)&Ws[trow * GPAD + tk + 8] = *(const uint4*)(wp + 8);
            }
            __syncthreads();
#pragma unroll
            for (int kh = 0; kh < 2; ++kh) {
                short8 af = *(const short8*)&As[(wv * 16 + L) * GPAD + kh * 32 + quad * 8];
#pragma unroll
                for (int cb = 0; cb < 4; ++cb) {
                    short8 bf = *(const short8*)&Ws[(cb * 16 + L) * GPAD + kh * 32 + quad * 8];
                    acc[cb] = __builtin_amdgcn_mfma_f32_16x16x32_bf16(af, bf, acc[cb], 0, 0, 0);
                }
            }
            __syncthreads();
        }
#pragma unroll
        for (int cb = 0; cb < 4; ++cb) {
            int col = n0 + cb * 16 + L;
            float bv = in_b[col];
#pragma unroll
            for (int i = 0; i < 4; ++i) {
                int m = m0 + wv * 16 + quad * 4 + i;
                if (m < NROW)
                    qkv16[(size_t)m * 768 + col] = (ushort_t)f2bf1((acc[cb][i] + bv) * oscale);
            }
        }
    } else {
        // -------- value-projection: 64 rows x 256 cols, A fetched once -----
        const int vb = bid - 684;        // 0..703
        const int m0 = vb * 64;

        const int  mrow = m0 + trow;
        const bool mv   = (mrow < VROWS);
        const float* arow = mem + (size_t)mrow * 256 + tk;

        f32x4 acc[16];
#pragma unroll
        for (int i = 0; i < 16; ++i) acc[i] = (f32x4){0.f, 0.f, 0.f, 0.f};

        for (int k0 = 0; k0 < 256; k0 += 64) {
            // stage A tile (bf16-converted)
            uint4 u0, u1;
            if (mv) {
                const float* ap = arow + k0;
                float4 a0 = *(const float4*)(ap + 0);
                float4 a1 = *(const float4*)(ap + 4);
                float4 a2 = *(const float4*)(ap + 8);
                float4 a3 = *(const float4*)(ap + 12);
                u0.x = pack2bf(a0.x, a0.y); u0.y = pack2bf(a0.z, a0.w);
                u0.z = pack2bf(a1.x, a1.y); u0.w = pack2bf(a1.z, a1.w);
                u1.x = pack2bf(a2.x, a2.y); u1.y = pack2bf(a2.z, a2.w);
                u1.z = pack2bf(a3.x, a3.y); u1.w = pack2bf(a3.z, a3.w);
            } else {
                u0 = make_uint4(0u, 0u, 0u, 0u); u1 = u0;
            }
            *(uint4*)&As[trow * GPAD + tk + 0] = u0;
            *(uint4*)&As[trow * GPAD + tk + 8] = u1;
            // stage W rows 0..127
#pragma unroll
            for (int wg = 0; wg < 2; ++wg) {
                int n = wg * 64 + trow;
                const ushort_t* wp = vp_wb + (size_t)n * 256 + k0 + tk;
                *(uint4*)&Ws[n * GPAD + tk + 0] = *(const uint4*)(wp + 0);
                *(uint4*)&Ws[n * GPAD + tk + 8] = *(const uint4*)(wp + 8);
            }
            __syncthreads();
#pragma unroll
            for (int kh = 0; kh < 2; ++kh) {
                short8 af = *(const short8*)&As[(wv * 16 + L) * GPAD + kh * 32 + quad * 8];
#pragma unroll
                for (int cb = 0; cb < 8; ++cb) {
                    short8 bf = *(const short8*)&Ws[(cb * 16 + L) * GPAD + kh * 32 + quad * 8];
                    acc[cb] = __builtin_amdgcn_mfma_f32_16x16x32_bf16(af, bf, acc[cb], 0, 0, 0);
                }
            }
            __syncthreads();
            // stage W rows 128..255 (same Ws buffer)
#pragma unroll
            for (int wg = 0; wg < 2; ++wg) {
                int n = wg * 64 + trow;
                const ushort_t* wp = vp_wb + (size_t)(128 + n) * 256 + k0 + tk;
                *(uint4*)&Ws[n * GPAD + tk + 0] = *(const uint4*)(wp + 0);
                *(uint4*)&Ws[n * GPAD + tk + 8] = *(const uint4*)(wp + 8);
            }
            __syncthreads();
#pragma unroll
            for (int kh = 0; kh < 2; ++kh) {
                short8 af = *(const short8*)&As[(wv * 16 + L) * GPAD + kh * 32 + quad * 8];
#pragma unroll
                for (int cb = 0; cb < 8; ++cb) {
                    short8 bf = *(const short8*)&Ws[(cb * 16 + L) * GPAD + kh * 32 + quad * 8];
                    acc[8 + cb] = __builtin_amdgcn_mfma_f32_16x16x32_bf16(af, bf, acc[8 + cb], 0, 0, 0);
                }
            }
            __syncthreads();
        }

        // epilogue: bias + bf16, repack through LDS (two 128-col passes)
        ushort_t* Cs = Ws;   // 64 rows x 136 stride = 17408 B (fits 18432)
#pragma unroll
        for (int half = 0; half < 2; ++half) {
            if (half) __syncthreads();
#pragma unroll
            for (int cb = 0; cb < 8; ++cb) {
                int col = cb * 16 + L;
                float bv = vp_b[half * 128 + col];
#pragma unroll
                for (int i = 0; i < 4; ++i) {
                    int r = wv * 16 + quad * 4 + i;
                    Cs[r * 136 + col] = (ushort_t)f2bf1(acc[half * 8 + cb][i] + bv);
                }
            }
            __syncthreads();
            {
                int r  = t >> 2;
                int ch = (t & 3) * 32;
                int m  = m0 + r;
                if (m < VROWS) {
                    const ushort_t* src = &Cs[r * 136 + ch];
                    uint4* dst = (uint4*)(value16 + (size_t)m * 256 + half * 128 + ch);
#pragma unroll
                    for (int j = 0; j < 4; ++j)
                        dst[j] = *(const uint4*)(src + j * 8);
                }
            }
        }
    }
}

// ---------------------------------------------------------------------------
// MFMA flash self-attention, bf16 in / bf16 out (unchanged).
// ---------------------------------------------------------------------------
__global__ __launch_bounds__(256) void sa_flash16(
    const ushort_t* __restrict__ qkv, ushort_t* __restrict__ attn_out)
{
    __shared__ ushort_t Ks[2 * 2080];
    __shared__ ushort_t Vt[2 * 2304];
    __shared__ ushort_t Ps[4 * 1152];

    const int t    = threadIdx.x;
    const int q0   = blockIdx.x * 64;
    const int b    = blockIdx.y & 3;
    const int h    = blockIdx.y >> 2;
    const int wv   = t >> 6;
    const int ln   = t & 63;
    const int L    = ln & 15;
    const int quad = ln >> 4;

    union { uint4 u; short8 s; } qu;
    qu.u = make_uint4(0u, 0u, 0u, 0u);
    {
        int q = q0 + wv * 16 + L;
        if (q < NQ)
            qu.u = *(const uint4*)(qkv + ((size_t)q * 4 + b) * 768 + h * 32 + quad * 8);
    }
    const short8 qf = qu.s;

    float mrun = -1e30f, lrun = 0.f;
    f32x4 oacc[2] = {{0.f,0.f,0.f,0.f},{0.f,0.f,0.f,0.f}};

    const int skey = t >> 2;
    const int sdg  = t & 3;

    uint4 ku, vu;
    auto kv_load = [&](int k0) {
        int kg = k0 + skey;
        ku = make_uint4(0u, 0u, 0u, 0u);
        vu = make_uint4(0u, 0u, 0u, 0u);
        if (kg < NQ) {
            const ushort_t* base = qkv + ((size_t)kg * 4 + b) * 768 + 256 + h * 32 + sdg * 8;
            ku = *(const uint4*)base;
            vu = *(const uint4*)(base + 256);
        }
    };

    kv_load(0);
    int it = 0;
    for (int k0 = 0; k0 < NQ; k0 += 64, it ^= 1) {
        *(uint4*)&Ks[it * 2080 + sdg * 520 + skey * 8] = ku;
        {
            ushort_t* vp = &Vt[it * 2304 + sdg * 8 * 72 + skey];
            vp[0 * 72] = (ushort_t)(vu.x & 0xffffu);
            vp[1 * 72] = (ushort_t)(vu.x >> 16);
            vp[2 * 72] = (ushort_t)(vu.y & 0xffffu);
            vp[3 * 72] = (ushort_t)(vu.y >> 16);
            vp[4 * 72] = (ushort_t)(vu.z & 0xffffu);
            vp[5 * 72] = (ushort_t)(vu.z >> 16);
            vp[6 * 72] = (ushort_t)(vu.w & 0xffffu);
            vp[7 * 72] = (ushort_t)(vu.w >> 16);
        }
        __syncthreads();
        if (k0 + 64 < NQ) kv_load(k0 + 64);

        f32x4 sacc[4] = {{0.f,0.f,0.f,0.f},{0.f,0.f,0.f,0.f},
                         {0.f,0.f,0.f,0.f},{0.f,0.f,0.f,0.f}};
#pragma unroll
        for (int cb = 0; cb < 4; ++cb) {
            short8 kf = *(const short8*)&Ks[it * 2080 + quad * 520 + (cb * 16 + L) * 8];
            sacc[cb] = __builtin_amdgcn_mfma_f32_16x16x32_bf16(kf, qf, sacc[cb], 0, 0, 0);
        }
        if (k0 + 64 > NQ) {
#pragma unroll
            for (int cb = 0; cb < 4; ++cb)
#pragma unroll
                for (int i = 0; i < 4; ++i)
                    if (k0 + cb * 16 + quad * 4 + i >= NQ) sacc[cb][i] = -1e30f;
        }

        float ml = -1e30f;
#pragma unroll
        for (int cb = 0; cb < 4; ++cb)
#pragma unroll
            for (int i = 0; i < 4; ++i) ml = fmaxf(ml, sacc[cb][i]);
        ml = fmaxf(ml, __shfl_xor(ml, 16, 64));
        ml = fmaxf(ml, __shfl_xor(ml, 32, 64));
        float mnew  = fmaxf(mrun, ml);
        float alpha = __expf(mrun - mnew);
        float p[16];
        float rs = 0.f;
#pragma unroll
        for (int cb = 0; cb < 4; ++cb)
#pragma unroll
            for (int i = 0; i < 4; ++i) {
                float e = __expf(sacc[cb][i] - mnew);
                p[cb * 4 + i] = e;
                rs += e;
            }
        rs += __shfl_xor(rs, 16, 64);
        rs += __shfl_xor(rs, 32, 64);
        lrun = lrun * alpha + rs;
        mrun = mnew;

        {
            ushort_t* pw = &Ps[wv * 1152 + L * 72];
#pragma unroll
            for (int cb = 0; cb < 4; ++cb) {
                uint2 u;
                u.x = pack2bf(p[cb * 4 + 0], p[cb * 4 + 1]);
                u.y = pack2bf(p[cb * 4 + 2], p[cb * 4 + 3]);
                *(uint2*)&pw[cb * 16 + quad * 4] = u;
            }
        }
#pragma unroll
        for (int i = 0; i < 4; ++i) {
            float ai = __shfl(alpha, quad * 4 + i, 64);
            oacc[0][i] *= ai;
            oacc[1][i] *= ai;
        }
        __syncthreads();

#pragma unroll
        for (int ks = 0; ks < 2; ++ks) {
            short8 pf = *(const short8*)&Ps[wv * 1152 + L * 72 + ks * 32 + quad * 8];
#pragma unroll
            for (int db = 0; db < 2; ++db) {
                short8 vf = *(const short8*)&Vt[it * 2304 + (db * 16 + L) * 72 + ks * 32 + quad * 8];
                oacc[db] = __builtin_amdgcn_mfma_f32_16x16x32_bf16(pf, vf, oacc[db], 0, 0, 0);
            }
        }
    }

#pragma unroll
    for (int i = 0; i < 4; ++i) {
        float lq = __shfl(lrun, quad * 4 + i, 64);
        float li = 1.f / lq;
        int q = q0 + wv * 16 + quad * 4 + i;
        if (q < NQ) {
            ushort_t* op = attn_out + ((size_t)q * 4 + b) * 256 + h * 32 + L;
            op[0]  = (ushort_t)f2bf1(oacc[0][i] * li);
            op[16] = (ushort_t)f2bf1(oacc[1][i] * li);
        }
    }
}

// ---------------------------------------------------------------------------
// gemm_ln16 (R13): fused  C = LN(resid + A@W^T + bias)  for N = 256.
// 16 rows x 256 cols per block -> grid = 3600/16 = 225 blocks (all CUs busy;
// R12's 57-block version left 78% of the GPU idle -> 73 us each).
// Wave wv owns cols [wv*64, wv*64+64); LN stats: intra-wave shfl_xor over the
// 16 L-lanes, then a 4-wave LDS reduction. Exact fp32 throughout.
// ---------------------------------------------------------------------------
__global__ __launch_bounds__(256) void gemm_ln16(
    const ushort_t* __restrict__ A, const ushort_t* __restrict__ W,
    const float* __restrict__ bias, const float* __restrict__ resid,
    const float* __restrict__ gam, const float* __restrict__ bet,
    float* __restrict__ out, const float* __restrict__ pos,
    ushort_t* __restrict__ out2, int M, int K)
{
    __shared__ ushort_t As[16 * GPAD];    //  2304 B
    __shared__ ushort_t Ws[256 * GPAD];   // 36864 B
    __shared__ float sS[4][16];
    __shared__ float s2S[4][16];

    const int t  = threadIdx.x;
    const int m0 = blockIdx.x * 16;
    const int trow = t >> 2;
    const int tk   = (t & 3) << 4;
    const int wv   = t >> 6;
    const int ln   = t & 63;
    const int L    = ln & 15;
    const int quad = ln >> 4;

    f32x4 acc[4] = {{0.f,0.f,0.f,0.f},{0.f,0.f,0.f,0.f},
                    {0.f,0.f,0.f,0.f},{0.f,0.f,0.f,0.f}};

    for (int k0 = 0; k0 < K; k0 += 64) {
        // stage A: 16 rows x 64 k (threads 0..127, one uint4 each)
        if (t < 128) {
            int r = t >> 3, seg = (t & 7) * 8;
            int m = m0 + r;
            uint4 a = make_uint4(0u, 0u, 0u, 0u);
            if (m < M) a = *(const uint4*)(A + (size_t)m * K + k0 + seg);
            *(uint4*)&As[r * GPAD + seg] = a;
        }
        // stage W: 256 rows x 64 k
#pragma unroll
        for (int wg = 0; wg < 4; ++wg) {
            int n = wg * 64 + trow;
            const ushort_t* wp = W + (size_t)n * K + k0 + tk;
            *(uint4*)&Ws[n * GPAD + tk + 0] = *(const uint4*)(wp + 0);
            *(uint4*)&Ws[n * GPAD + tk + 8] = *(const uint4*)(wp + 8);
        }
        __syncthreads();
#pragma unroll
        for (int kh = 0; kh < 2; ++kh) {
            short8 af = *(const short8*)&As[L * GPAD + kh * 32 + quad * 8];
#pragma unroll
            for (int cb = 0; cb < 4; ++cb) {
                short8 bf = *(const short8*)&Ws[(wv * 64 + cb * 16 + L) * GPAD + kh * 32 + quad * 8];
                acc[cb] = __builtin_amdgcn_mfma_f32_16x16x32_bf16(af, bf, acc[cb], 0, 0, 0);
            }
        }
        __syncthreads();
    }

    // ---- fused LN epilogue ----
    float s[4]  = {0.f, 0.f, 0.f, 0.f};
    float s2[4] = {0.f, 0.f, 0.f, 0.f};
#pragma unroll
    for (int cb = 0; cb < 4; ++cb) {
        int col = wv * 64 + cb * 16 + L;
        float bv = bias[col];
#pragma unroll
        for (int i = 0; i < 4; ++i) {
            int m = m0 + quad * 4 + i;
            float r = (m < M) ? resid[(size_t)m * 256 + col] : 0.f;
            float xv = acc[cb][i] + bv + r;
            acc[cb][i] = xv;
            s[i]  += xv;
            s2[i] += xv * xv;
        }
    }
#pragma unroll
    for (int off = 1; off < 16; off <<= 1) {
#pragma unroll
        for (int i = 0; i < 4; ++i) {
            s[i]  += __shfl_xor(s[i],  off, 64);
            s2[i] += __shfl_xor(s2[i], off, 64);
        }
    }
    if (L == 0) {
#pragma unroll
        for (int i = 0; i < 4; ++i) {
            sS[wv][quad * 4 + i]  = s[i];
            s2S[wv][quad * 4 + i] = s2[i];
        }
    }
    __syncthreads();
    float mean[4], rstd[4];
#pragma unroll
    for (int i = 0; i < 4; ++i) {
        int row = quad * 4 + i;
        float St  = sS[0][row]  + sS[1][row]  + sS[2][row]  + sS[3][row];
        float S2t = s2S[0][row] + s2S[1][row] + s2S[2][row] + s2S[3][row];
        mean[i] = St * (1.f / 256.f);
        float var = S2t * (1.f / 256.f) - mean[i] * mean[i];
        rstd[i] = rsqrtf(var + 1e-5f);
    }
#pragma unroll
    for (int cb = 0; cb < 4; ++cb) {
        int col = wv * 64 + cb * 16 + L;
        float gv = gam[col];
        float bt = bet[col];
#pragma unroll
        for (int i = 0; i < 4; ++i) {
            int m = m0 + quad * 4 + i;
            if (m < M) {
                float y = (acc[cb][i] - mean[i]) * rstd[i] * gv + bt;
                out[(size_t)m * 256 + col] = y;
                if (out2) {
                    float o2 = y + (pos ? pos[(size_t)m * 256 + col] : 0.f);
                    out2[(size_t)m * 256 + col] = (ushort_t)f2bf1(o2);
                }
            }
        }
    }
}

// ---------------------------------------------------------------------------
// Fused offset + attention-weight GEMM (bf16 weights).
// ---------------------------------------------------------------------------
__global__ __launch_bounds__(256) void offaw16(
    const ushort_t* __restrict__ A,
    const ushort_t* __restrict__ off_wb, const float* __restrict__ off_b,
    const ushort_t* __restrict__ aw_wb, const float* __restrict__ aw_b,
    float* __restrict__ off_raw, float* __restrict__ aw_raw)
{
    __shared__ ushort_t As[64 * GPAD];
    __shared__ ushort_t Ws[64 * GPAD];

    const int t  = threadIdx.x;
    const int m0 = blockIdx.x * 64;
    const int by = blockIdx.y;
    const bool isaw = (by >= 4);
    const int n0 = isaw ? (by - 4) * 64 : by * 64;
    const ushort_t* W = isaw ? aw_wb : off_wb;
    const float* bs = isaw ? aw_b : off_b;
    float* C = isaw ? aw_raw : off_raw;
    const int ldc = isaw ? 128 : 256;

    const int trow = t >> 2;
    const int tk   = (t & 3) << 4;
    const int wv   = t >> 6;
    const int ln   = t & 63;
    const int L    = ln & 15;
    const int quad = ln >> 4;

    const int  mrow = m0 + trow;
    const bool mv   = (mrow < NROW);
    const ushort_t* arow = A + (size_t)mrow * 256 + tk;
    const ushort_t* wrow = W + (size_t)(n0 + trow) * 256 + tk;

    f32x4 acc[4] = {{0.f,0.f,0.f,0.f},{0.f,0.f,0.f,0.f},
                    {0.f,0.f,0.f,0.f},{0.f,0.f,0.f,0.f}};

    for (int k0 = 0; k0 < 256; k0 += 64) {
        {
            uint4 a0 = make_uint4(0u,0u,0u,0u), a1 = a0;
            if (mv) {
                a0 = *(const uint4*)(arow + k0);
                a1 = *(const uint4*)(arow + k0 + 8);
            }
            *(uint4*)&As[trow * GPAD + tk + 0] = a0;
            *(uint4*)&As[trow * GPAD + tk + 8] = a1;
        }
        {
            const ushort_t* wp = wrow + k0;
            *(uint4*)&Ws[trow * GPAD + tk + 0] = *(const uint4*)(wp + 0);
            *(uint4*)&Ws[trow * GPAD + tk + 8] = *(const uint4*)(wp + 8);
        }
        __syncthreads();
#pragma unroll
        for (int kh = 0; kh < 2; ++kh) {
            short8 af = *(const short8*)&As[(wv * 16 + L) * GPAD + kh * 32 + quad * 8];
#pragma unroll
            for (int cb = 0; cb < 4; ++cb) {
                short8 bf = *(const short8*)&Ws[(cb * 16 + L) * GPAD + kh * 32 + quad * 8];
                acc[cb] = __builtin_amdgcn_mfma_f32_16x16x32_bf16(af, bf, acc[cb], 0, 0, 0);
            }
        }
        __syncthreads();
    }
#pragma unroll
    for (int cb = 0; cb < 4; ++cb) {
        int col = n0 + cb * 16 + L;
        float bv = bs[col];
#pragma unroll
        for (int i = 0; i < 4; ++i) {
            int m = m0 + wv * 16 + quad * 4 + i;
            if (m < NROW)
                C[(size_t)m * ldc + col] = acc[cb][i] + bv;
        }
    }
}

// ---------------------------------------------------------------------------
// Generic A-bf16, W-bf16 -> C-bf16 GEMM (FFN1 with ReLU).
// ---------------------------------------------------------------------------
__global__ __launch_bounds__(256) void gemm16_16(
    const ushort_t* __restrict__ A, const ushort_t* __restrict__ W,
    const float* __restrict__ bias, ushort_t* __restrict__ C,
    int M, int N, int K, int ldc, int relu)
{
    __shared__ ushort_t As[64 * GPAD];
    __shared__ ushort_t Ws[64 * GPAD];

    const int t  = threadIdx.x;
    const int m0 = blockIdx.x * 64;
    const int n0 = blockIdx.y * 64;
    const int trow = t >> 2;
    const int tk   = (t & 3) << 4;
    const int wv   = t >> 6;
    const int ln   = t & 63;
    const int L    = ln & 15;
    const int quad = ln >> 4;

    const int  mrow = m0 + trow;
    const bool mv   = (mrow < M);
    const ushort_t* arow = A + (size_t)mrow * K + tk;
    const ushort_t* wrow = W + (size_t)(n0 + trow) * K + tk;

    f32x4 acc[4] = {{0.f,0.f,0.f,0.f},{0.f,0.f,0.f,0.f},
                    {0.f,0.f,0.f,0.f},{0.f,0.f,0.f,0.f}};

    for (int k0 = 0; k0 < K; k0 += 64) {
        {
            uint4 a0 = make_uint4(0u,0u,0u,0u), a1 = a0;
            if (mv) {
                a0 = *(const uint4*)(arow + k0);
                a1 = *(const uint4*)(arow + k0 + 8);
            }
            *(uint4*)&As[trow * GPAD + tk + 0] = a0;
            *(uint4*)&As[trow * GPAD + tk + 8] = a1;
        }
        {
            const ushort_t* wp = wrow + k0;
            *(uint4*)&Ws[trow * GPAD + tk + 0] = *(const uint4*)(wp + 0);
            *(uint4*)&Ws[trow * GPAD + tk + 8] = *(const uint4*)(wp + 8);
        }
        __syncthreads();
#pragma unroll
        for (int kh = 0; kh < 2; ++kh) {
            short8 af = *(const short8*)&As[(wv * 16 + L) * GPAD + kh * 32 + quad * 8];
#pragma unroll
            for (int cb = 0; cb < 4; ++cb) {
                short8 bf = *(const short8*)&Ws[(cb * 16 + L) * GPAD + kh * 32 + quad * 8];
                acc[cb] = __builtin_amdgcn_mfma_f32_16x16x32_bf16(af, bf, acc[cb], 0, 0, 0);
            }
        }
        __syncthreads();
    }
#pragma unroll
    for (int cb = 0; cb < 4; ++cb) {
        int col = n0 + cb * 16 + L;
        float bv = bias[col];
#pragma unroll
        for (int i = 0; i < 4; ++i) {
            int m = m0 + wv * 16 + quad * 4 + i;
            if (m < M) {
                float o = acc[cb][i] + bv;
                if (relu) o = fmaxf(o, 0.f);
                C[(size_t)m * ldc + col] = (ushort_t)f2bf1(o);
            }
        }
    }
}

// ---------------------------------------------------------------------------
// Multi-scale deformable sampling (unchanged).
// ---------------------------------------------------------------------------
__global__ __launch_bounds__(256) void msdeform16(
    const float* __restrict__ off_raw, const float* __restrict__ aw_raw,
    const float* __restrict__ refp, const ushort_t* __restrict__ value,
    ushort_t* __restrict__ out)
{
    const int row = blockIdx.x;   // q*4+b
    const int b = row & 3;
    const int t = threadIdx.x;

    __shared__ float aw_s[8][17];
    __shared__ float px_s[8][16];
    __shared__ float py_s[8][16];

    const int Hs[4]  = {92, 46, 23, 12};
    const int Wd[4]  = {92, 46, 23, 12};
    const int S0_[4] = {0, 8464, 10580, 11109};

    if (t < 128) {
        int hh = t >> 4, lp = t & 15, l = lp >> 2;
        float ox = off_raw[(size_t)row * 256 + hh * 32 + lp * 2 + 0];
        float oy = off_raw[(size_t)row * 256 + hh * 32 + lp * 2 + 1];
        float rx = refp[((size_t)row * 4 + l) * 2 + 0];
        float ry = refp[((size_t)row * 4 + l) * 2 + 1];
        px_s[hh][lp] = rx * (float)Wd[l] + ox - 0.5f;
        py_s[hh][lp] = ry * (float)Hs[l] + oy - 0.5f;
    }
    if (t < 8) {
        int hh = t;
        float v[16];
        float m = -1e30f;
#pragma unroll
        for (int j = 0; j < 16; ++j) {
            v[j] = aw_raw[(size_t)row * 128 + hh * 16 + j];
            m = fmaxf(m, v[j]);
        }
        float ssum = 0.f;
#pragma unroll
        for (int j = 0; j < 16; ++j) { v[j] = __expf(v[j] - m); ssum += v[j]; }
        float inv = 1.f / ssum;
#pragma unroll
        for (int j = 0; j < 16; ++j) aw_s[hh][j] = v[j] * inv;
    }
    __syncthreads();

    const int h = t >> 5, d = t & 31;
    const ushort_t* vb = value + (size_t)b * 256 + h * 32 + d;
    float acc = 0.f;
#pragma unroll
    for (int l = 0; l < 4; ++l) {
        const int H = Hs[l], W = Wd[l], base = S0_[l];
#pragma unroll
        for (int p = 0; p < 4; ++p) {
            const int lp = l * 4 + p;
            float px = px_s[h][lp], py = py_s[h][lp];
            float x0f = floorf(px), y0f = floorf(py);
            int x0 = (int)x0f, y0 = (int)y0f;
            float wx = px - x0f, wy = py - y0f;
            float sv = 0.f;
#pragma unroll
            for (int dy = 0; dy < 2; ++dy) {
#pragma unroll
                for (int dx = 0; dx < 2; ++dx) {
                    int xi = x0 + dx, yi = y0 + dy;
                    float flag = (xi >= 0 && xi < W && yi >= 0 && yi < H) ? 1.f : 0.f;
                    int xc = xi < 0 ? 0 : (xi >= W ? W - 1 : xi);
                    int yc = yi < 0 ? 0 : (yi >= H ? H - 1 : yi);
                    float wgt = (dx ? wx : 1.f - wx) * (dy ? wy : 1.f - wy);
                    float gv = bf2f(vb[(size_t)(base + yc * W + xc) * 1024]);
                    sv = fmaf(wgt * flag, gv, sv);
                }
            }
            acc = fmaf(aw_s[h][lp], sv, acc);
        }
    }
    out[(size_t)row * 256 + h * 32 + d] = (ushort_t)f2bf1(acc);
}

// ---------------------------------------------------------------------------
extern "C" void kernel_launch(void* const* d_in, const int* in_sizes, int n_in,
                              void* d_out, int out_size, void* d_ws, size_t ws_size,
                              hipStream_t stream)
{
    const float* tgt    = (const float*)d_in[0];
    const float* qpos   = (const float*)d_in[1];
    const float* refp   = (const float*)d_in[2];
    const float* mem    = (const float*)d_in[3];
    const float* in_w   = (const float*)d_in[6];
    const float* in_b   = (const float*)d_in[7];
    const float* outp_w = (const float*)d_in[8];
    const float* outp_b = (const float*)d_in[9];
    const float* off_w  = (const float*)d_in[10];
    const float* off_b  = (const float*)d_in[11];
    const float* aw_w   = (const float*)d_in[12];
    const float* aw_b   = (const float*)d_in[13];
    const float* vp_w   = (const float*)d_in[14];
    const float* vp_b   = (const float*)d_in[15];
    const float* op_w   = (const float*)d_in[16];
    const float* op_b   = (const float*)d_in[17];
    const float* ln1g   = (const float*)d_in[18];
    const float* ln1b   = (const float*)d_in[19];
    const float* ln2g   = (const float*)d_in[20];
    const float* ln2b   = (const float*)d_in[21];
    const float* ln3g   = (const float*)d_in[22];
    const float* ln3b   = (const float*)d_in[23];
    const float* l1w    = (const float*)d_in[24];
    const float* l1b    = (const float*)d_in[25];
    const float* l2w    = (const float*)d_in[26];
    const float* l2b    = (const float*)d_in[27];
    float* out = (float*)d_out;
    float* ws  = (float*)d_ws;

    // workspace layout (float units)
    ushort_t* qkv16    = (ushort_t*)ws;                 // 691200 floats
    ushort_t* att16    = (ushort_t*)(ws + 691200);      // 230400
    float*    tgt_a    = ws + 1843200;                  // 921600
    ushort_t* xca16    = (ushort_t*)(ws + 2764800);     // 230400
    float*    off_raw  = ws + 2995200;                  // 921600
    float*    aw_raw   = ws + 3916800;                  // 460800
    ushort_t* att2_16  = (ushort_t*)(ws + 4377600);     // 230400
    float*    tgt_b    = ws + 4608000;                  // 921600
    ushort_t* tgtb16   = (ushort_t*)(ws + 5529600);     // 230400
    ushort_t* value16  = (ushort_t*)(ws + 5760000);     // 5761536
    ushort_t* hidden16 = (ushort_t*)(ws + 11521536);    // 1843200
    ushort_t* wb       = (ushort_t*)(ws + 13364736);    // 507904 (bf16 weights)

    const ushort_t* in_wb   = wb + WB_IN;
    const ushort_t* vp_wb   = wb + WB_VP;
    const ushort_t* outp_wb = wb + WB_OUTP;
    const ushort_t* off_wb  = wb + WB_OFF;
    const ushort_t* aw_wb   = wb + WB_AW;
    const ushort_t* op_wb   = wb + WB_OP;
    const ushort_t* l1_wb   = wb + WB_L1;
    const ushort_t* l2_wb   = wb + WB_L2;

    dim3 b256(256);

    // 0. one-shot weight conversion fp32 -> bf16
    hipLaunchKernelGGL(cvt_weights, dim3(496), b256, 0, stream,
                       in_w, vp_w, outp_w, off_w, aw_w, op_w, l1w, l2w, wb);
    // 1. qkv + value projection (vproj full-width: A fetched once)
    hipLaunchKernelGGL(proj_fused, dim3(1388), b256, 0, stream,
                       tgt, qpos, in_wb, in_b, mem, vp_wb, vp_b, qkv16, value16);
    // 2. flash self-attention
    hipLaunchKernelGGL(sa_flash16, dim3(15, 32), b256, 0, stream, qkv16, att16);
    // 3. out-proj + LN2 fused: tgt_a = LN(tgt + attn@W + b); xca16 = bf16(tgt_a + qpos)
    hipLaunchKernelGGL(gemm_ln16, dim3(225), b256, 0, stream,
                       att16, outp_wb, outp_b, tgt, ln2g, ln2b,
                       tgt_a, qpos, xca16, NROW, 256);
    // 4. fused sampling-offset + attention-weight GEMMs
    hipLaunchKernelGGL(offaw16, dim3(57, 6), b256, 0, stream,
                       xca16, off_wb, off_b, aw_wb, aw_b, off_raw, aw_raw);
    // 5. deformable sampling (bf16 out)
    hipLaunchKernelGGL(msdeform16, dim3(3600), b256, 0, stream,
                       off_raw, aw_raw, refp, value16, att2_16);
    // 6. oproj + LN1 fused: tgt_b = LN(tgt_a + ca@W + b); tgtb16 = bf16(tgt_b)
    hipLaunchKernelGGL(gemm_ln16, dim3(225), b256, 0, stream,
                       att2_16, op_wb, op_b, tgt_a, ln1g, ln1b,
                       tgt_b, (const float*)nullptr, tgtb16, NROW, 256);
    // 7. FFN1 + ReLU (bf16 out)
    hipLaunchKernelGGL(gemm16_16, dim3(57, 16), b256, 0, stream,
                       tgtb16, l1_wb, l1b, hidden16, NROW, 1024, 256, 1024, 1);
    // 8. FFN2 + LN3 fused -> d_out
    hipLaunchKernelGGL(gemm_ln16, dim3(225), b256, 0, stream,
                       hidden16, l2_wb, l2b, tgt_b, ln3g, ln3b,
                       out, (const float*)nullptr, (ushort_t*)nullptr, NROW, 1024);
}

// Round 4
// 266.964 us; speedup vs baseline: 1.3470x; 1.0347x over previous
//
#include <hip/hip_runtime.h>
#include <math.h>

#define D_MODEL 256
#define NHEAD   8
#define NLVL    4
#define NPTS    4
#define DHEAD   32
#define DFFN    1024
#define NQ      900
#define BSZ     4
#define NROW    (NQ * BSZ)      // 3600
#define S_TOT   11253
#define VROWS   (S_TOT * BSZ)   // 45012
#define SASCALE 0.17677669529663687f

typedef __attribute__((ext_vector_type(8))) short short8;
typedef __attribute__((ext_vector_type(4))) float f32x4;
typedef unsigned short ushort_t;

static __device__ __forceinline__ unsigned f2bf1(float f) {
    unsigned u = __float_as_uint(f);
    return (u + 0x7FFFu + ((u >> 16) & 1u)) >> 16;
}
static __device__ __forceinline__ unsigned pack2bf(float x, float y) {
    return f2bf1(x) | (f2bf1(y) << 16);
}
static __device__ __forceinline__ float bf2f(ushort_t u) {
    return __uint_as_float(((unsigned)u) << 16);
}

#define GPAD 72

// --------------------------------------------------------------------------
// R14: W path = pre-swizzled weights + global_load_lds direct staging.
// cvt_weights stores W with 16B chunk c -> c ^ (n&7) inside every aligned
// 64-element k-group. GEMM kernels stage W linearly into LDS ([rows][64]
// shorts) via global_load_lds (no VGPR round-trip, no per-pair vmcnt wait),
// and MFMA reads XOR the same involution -> bank-conflict-free (8/bank =
// floor). A staging (small) stays reg-based with GPAD padding.
// --------------------------------------------------------------------------
#if __has_builtin(__builtin_amdgcn_global_load_lds)
#define HAS_GLL 1
#endif

static __device__ __forceinline__ void stage_w16(const ushort_t* g, ushort_t* ldsbase, int lane)
{
#ifdef HAS_GLL
    __builtin_amdgcn_global_load_lds(
        (const __attribute__((address_space(1))) unsigned int*)g,
        (__attribute__((address_space(3))) unsigned int*)ldsbase, 16, 0, 0);
#else
    *(uint4*)(ldsbase + lane * 8) = *(const uint4*)g;
#endif
}

// bf16 weight buffer element offsets
#define WB_IN   0         // 768*256
#define WB_VP   196608    // 256*256
#define WB_OUTP 262144    // 256*256
#define WB_OFF  327680    // 256*256
#define WB_AW   393216    // 128*256
#define WB_OP   425984    // 256*256
#define WB_L1   491520    // 1024*256
#define WB_L2   753664    // 256*1024
#define WB_TOT  1015808

// ---------------------------------------------------------------------------
// One-shot fp32 -> bf16 conversion of all weight matrices, PRE-SWIZZLED:
// dst[n][k'] with k' = (k & ~63) | ((k&63) ^ ((n&7)<<3)).
// ---------------------------------------------------------------------------
__global__ __launch_bounds__(256) void cvt_weights(
    const float* __restrict__ w_in, const float* __restrict__ w_vp,
    const float* __restrict__ w_outp, const float* __restrict__ w_off,
    const float* __restrict__ w_aw, const float* __restrict__ w_op,
    const float* __restrict__ w_l1, const float* __restrict__ w_l2,
    ushort_t* __restrict__ dst)
{
    int b = blockIdx.x;
    const float* src;
    int dstoff;
    int kbits = 8;   // K = 256 default
    if (b < 96)       { src = w_in;   dstoff = WB_IN;   }
    else if (b < 128) { src = w_vp;   b -= 96;  dstoff = WB_VP;   }
    else if (b < 160) { src = w_outp; b -= 128; dstoff = WB_OUTP; }
    else if (b < 192) { src = w_off;  b -= 160; dstoff = WB_OFF;  }
    else if (b < 208) { src = w_aw;   b -= 192; dstoff = WB_AW;   }
    else if (b < 240) { src = w_op;   b -= 208; dstoff = WB_OP;   }
    else if (b < 368) { src = w_l1;   b -= 240; dstoff = WB_L1;   }
    else              { src = w_l2;   b -= 368; dstoff = WB_L2;   kbits = 10; }
    int i = (b * 256 + threadIdx.x) * 8;      // one aligned 16B chunk
    float4 f0 = *(const float4*)(src + i);
    float4 f1 = *(const float4*)(src + i + 4);
    uint4 u;
    u.x = pack2bf(f0.x, f0.y); u.y = pack2bf(f0.z, f0.w);
    u.z = pack2bf(f1.x, f1.y); u.w = pack2bf(f1.z, f1.w);
    int K = 1 << kbits;
    int n = i >> kbits;
    int k = i & (K - 1);
    int kswz = (k & ~63) | ((k & 63) ^ ((n & 7) << 3));
    *(uint4*)(dst + dstoff + (size_t)n * K + kswz) = u;
}

// ---------------------------------------------------------------------------
// proj_fused: qkv projection (blocks 0..683) + value projection (684..1387).
// W staging now via global_load_lds into linear LDS (swizzled read).
// ---------------------------------------------------------------------------
__global__ __launch_bounds__(256) void proj_fused(
    const float* __restrict__ tgt, const float* __restrict__ qpos,
    const ushort_t* __restrict__ in_wb, const float* __restrict__ in_b,
    const float* __restrict__ mem, const ushort_t* __restrict__ vp_wb,
    const float* __restrict__ vp_b,
    ushort_t* __restrict__ qkv16, ushort_t* __restrict__ value16)
{
    __shared__ ushort_t As[64 * GPAD];    // 9216 B
    __shared__ ushort_t Ws[8704];         // linear W tiles; also Cs repack

    const int t    = threadIdx.x;
    const int bid  = blockIdx.x;
    const int trow = t >> 2;
    const int tk   = (t & 3) << 4;
    const int wv   = t >> 6;
    const int ln   = t & 63;
    const int L    = ln & 15;
    const int quad = ln >> 4;
    const int swz  = (L & 7) << 3;        // read-side XOR (shorts)
    const int lrow = ln >> 3;             // gll: lane's row within 8-row group
    const int lchk = (ln & 7) << 3;       // gll: lane's 16B chunk (shorts)

    if (bid < 684) {
        // ---------------- QKV path (64x64 tiles) ----------------
        const int m0 = (bid % 57) * 64;
        const int n0 = (bid / 57) * 64;
        const bool addpos = (n0 < 512);
        const float oscale = (n0 < 256) ? SASCALE : 1.f;

        const int  mrow = m0 + trow;
        const bool mv   = (mrow < NROW);
        const float* arow = tgt  + (size_t)mrow * 256 + tk;
        const float* prow = qpos + (size_t)mrow * 256 + tk;

        f32x4 acc[4] = {{0.f,0.f,0.f,0.f},{0.f,0.f,0.f,0.f},
                        {0.f,0.f,0.f,0.f},{0.f,0.f,0.f,0.f}};

        for (int k0 = 0; k0 < 256; k0 += 64) {
            // W: 64 rows via gll (2 issues per wave)
#pragma unroll
            for (int j = 0; j < 2; ++j) {
                int r0 = (wv * 2 + j) * 8;
                const ushort_t* g = in_wb + (size_t)(n0 + r0 + lrow) * 256 + k0 + lchk;
                stage_w16(g, &Ws[r0 * 64], ln);
            }
            // A: fp32 (+pos) -> bf16 -> LDS (reg path)
            uint4 u0, u1;
            if (mv) {
                const float* ap = arow + k0;
                float4 a0 = *(const float4*)(ap + 0);
                float4 a1 = *(const float4*)(ap + 4);
                float4 a2 = *(const float4*)(ap + 8);
                float4 a3 = *(const float4*)(ap + 12);
                if (addpos) {
                    const float* pp = prow + k0;
                    float4 p0 = *(const float4*)(pp + 0);
                    float4 p1 = *(const float4*)(pp + 4);
                    float4 p2 = *(const float4*)(pp + 8);
                    float4 p3 = *(const float4*)(pp + 12);
                    a0.x += p0.x; a0.y += p0.y; a0.z += p0.z; a0.w += p0.w;
                    a1.x += p1.x; a1.y += p1.y; a1.z += p1.z; a1.w += p1.w;
                    a2.x += p2.x; a2.y += p2.y; a2.z += p2.z; a2.w += p2.w;
                    a3.x += p3.x; a3.y += p3.y; a3.z += p3.z; a3.w += p3.w;
                }
                u0.x = pack2bf(a0.x, a0.y); u0.y = pack2bf(a0.z, a0.w);
                u0.z = pack2bf(a1.x, a1.y); u0.w = pack2bf(a1.z, a1.w);
                u1.x = pack2bf(a2.x, a2.y); u1.y = pack2bf(a2.z, a2.w);
                u1.z = pack2bf(a3.x, a3.y); u1.w = pack2bf(a3.z, a3.w);
            } else {
                u0 = make_uint4(0u, 0u, 0u, 0u); u1 = u0;
            }
            *(uint4*)&As[trow * GPAD + tk + 0] = u0;
            *(uint4*)&As[trow * GPAD + tk + 8] = u1;
            __syncthreads();
#pragma unroll
            for (int kh = 0; kh < 2; ++kh) {
                short8 af = *(const short8*)&As[(wv * 16 + L) * GPAD + kh * 32 + quad * 8];
#pragma unroll
                for (int cb = 0; cb < 4; ++cb) {
                    short8 bf = *(const short8*)&Ws[(cb * 16 + L) * 64 + ((kh * 32 + quad * 8) ^ swz)];
                    acc[cb] = __builtin_amdgcn_mfma_f32_16x16x32_bf16(af, bf, acc[cb], 0, 0, 0);
                }
            }
            __syncthreads();
        }
#pragma unroll
        for (int cb = 0; cb < 4; ++cb) {
            int col = n0 + cb * 16 + L;
            float bv = in_b[col];
#pragma unroll
            for (int i = 0; i < 4; ++i) {
                int m = m0 + wv * 16 + quad * 4 + i;
                if (m < NROW)
                    qkv16[(size_t)m * 768 + col] = (ushort_t)f2bf1((acc[cb][i] + bv) * oscale);
            }
        }
    } else {
        // -------- value-projection: 64 rows x 256 cols, A fetched once -----
        const int vb = bid - 684;        // 0..703
        const int m0 = vb * 64;

        const int  mrow = m0 + trow;
        const bool mv   = (mrow < VROWS);
        const float* arow = mem + (size_t)mrow * 256 + tk;

        f32x4 acc[16];
#pragma unroll
        for (int i = 0; i < 16; ++i) acc[i] = (f32x4){0.f, 0.f, 0.f, 0.f};

        for (int k0 = 0; k0 < 256; k0 += 64) {
            // stage W rows 0..127 via gll (4 issues per wave)
#pragma unroll
            for (int j = 0; j < 4; ++j) {
                int r0 = (wv * 4 + j) * 8;
                const ushort_t* g = vp_wb + (size_t)(r0 + lrow) * 256 + k0 + lchk;
                stage_w16(g, &Ws[r0 * 64], ln);
            }
            // stage A tile (bf16-converted, reg path)
            uint4 u0, u1;
            if (mv) {
                const float* ap = arow + k0;
                float4 a0 = *(const float4*)(ap + 0);
                float4 a1 = *(const float4*)(ap + 4);
                float4 a2 = *(const float4*)(ap + 8);
                float4 a3 = *(const float4*)(ap + 12);
                u0.x = pack2bf(a0.x, a0.y); u0.y = pack2bf(a0.z, a0.w);
                u0.z = pack2bf(a1.x, a1.y); u0.w = pack2bf(a1.z, a1.w);
                u1.x = pack2bf(a2.x, a2.y); u1.y = pack2bf(a2.z, a2.w);
                u1.z = pack2bf(a3.x, a3.y); u1.w = pack2bf(a3.z, a3.w);
            } else {
                u0 = make_uint4(0u, 0u, 0u, 0u); u1 = u0;
            }
            *(uint4*)&As[trow * GPAD + tk + 0] = u0;
            *(uint4*)&As[trow * GPAD + tk + 8] = u1;
            __syncthreads();
#pragma unroll
            for (int kh = 0; kh < 2; ++kh) {
                short8 af = *(const short8*)&As[(wv * 16 + L) * GPAD + kh * 32 + quad * 8];
#pragma unroll
                for (int cb = 0; cb < 8; ++cb) {
                    short8 bf = *(const short8*)&Ws[(cb * 16 + L) * 64 + ((kh * 32 + quad * 8) ^ swz)];
                    acc[cb] = __builtin_amdgcn_mfma_f32_16x16x32_bf16(af, bf, acc[cb], 0, 0, 0);
                }
            }
            __syncthreads();
            // stage W rows 128..255 (same buffer)
#pragma unroll
            for (int j = 0; j < 4; ++j) {
                int r0 = (wv * 4 + j) * 8;
                const ushort_t* g = vp_wb + (size_t)(128 + r0 + lrow) * 256 + k0 + lchk;
                stage_w16(g, &Ws[r0 * 64], ln);
            }
            __syncthreads();
#pragma unroll
            for (int kh = 0; kh < 2; ++kh) {
                short8 af = *(const short8*)&As[(wv * 16 + L) * GPAD + kh * 32 + quad * 8];
#pragma unroll
                for (int cb = 0; cb < 8; ++cb) {
                    short8 bf = *(const short8*)&Ws[(cb * 16 + L) * 64 + ((kh * 32 + quad * 8) ^ swz)];
                    acc[8 + cb] = __builtin_amdgcn_mfma_f32_16x16x32_bf16(af, bf, acc[8 + cb], 0, 0, 0);
                }
            }
            __syncthreads();
        }

        // epilogue: bias + bf16, repack through LDS (two 128-col passes)
        ushort_t* Cs = Ws;   // 64 rows x 136 stride = 8704 shorts (exact fit)
#pragma unroll
        for (int half = 0; half < 2; ++half) {
            if (half) __syncthreads();
#pragma unroll
            for (int cb = 0; cb < 8; ++cb) {
                int col = cb * 16 + L;
                float bv = vp_b[half * 128 + col];
#pragma unroll
                for (int i = 0; i < 4; ++i) {
                    int r = wv * 16 + quad * 4 + i;
                    Cs[r * 136 + col] = (ushort_t)f2bf1(acc[half * 8 + cb][i] + bv);
                }
            }
            __syncthreads();
            {
                int r  = t >> 2;
                int ch = (t & 3) * 32;
                int m  = m0 + r;
                if (m < VROWS) {
                    const ushort_t* src = &Cs[r * 136 + ch];
                    uint4* dst = (uint4*)(value16 + (size_t)m * 256 + half * 128 + ch);
#pragma unroll
                    for (int j = 0; j < 4; ++j)
                        dst[j] = *(const uint4*)(src + j * 8);
                }
            }
        }
    }
}

// ---------------------------------------------------------------------------
// MFMA flash self-attention, bf16 in / bf16 out (unchanged).
// ---------------------------------------------------------------------------
__global__ __launch_bounds__(256) void sa_flash16(
    const ushort_t* __restrict__ qkv, ushort_t* __restrict__ attn_out)
{
    __shared__ ushort_t Ks[2 * 2080];
    __shared__ ushort_t Vt[2 * 2304];
    __shared__ ushort_t Ps[4 * 1152];

    const int t    = threadIdx.x;
    const int q0   = blockIdx.x * 64;
    const int b    = blockIdx.y & 3;
    const int h    = blockIdx.y >> 2;
    const int wv   = t >> 6;
    const int ln   = t & 63;
    const int L    = ln & 15;
    const int quad = ln >> 4;

    union { uint4 u; short8 s; } qu;
    qu.u = make_uint4(0u, 0u, 0u, 0u);
    {
        int q = q0 + wv * 16 + L;
        if (q < NQ)
            qu.u = *(const uint4*)(qkv + ((size_t)q * 4 + b) * 768 + h * 32 + quad * 8);
    }
    const short8 qf = qu.s;

    float mrun = -1e30f, lrun = 0.f;
    f32x4 oacc[2] = {{0.f,0.f,0.f,0.f},{0.f,0.f,0.f,0.f}};

    const int skey = t >> 2;
    const int sdg  = t & 3;

    uint4 ku, vu;
    auto kv_load = [&](int k0) {
        int kg = k0 + skey;
        ku = make_uint4(0u, 0u, 0u, 0u);
        vu = make_uint4(0u, 0u, 0u, 0u);
        if (kg < NQ) {
            const ushort_t* base = qkv + ((size_t)kg * 4 + b) * 768 + 256 + h * 32 + sdg * 8;
            ku = *(const uint4*)base;
            vu = *(const uint4*)(base + 256);
        }
    };

    kv_load(0);
    int it = 0;
    for (int k0 = 0; k0 < NQ; k0 += 64, it ^= 1) {
        *(uint4*)&Ks[it * 2080 + sdg * 520 + skey * 8] = ku;
        {
            ushort_t* vp = &Vt[it * 2304 + sdg * 8 * 72 + skey];
            vp[0 * 72] = (ushort_t)(vu.x & 0xffffu);
            vp[1 * 72] = (ushort_t)(vu.x >> 16);
            vp[2 * 72] = (ushort_t)(vu.y & 0xffffu);
            vp[3 * 72] = (ushort_t)(vu.y >> 16);
            vp[4 * 72] = (ushort_t)(vu.z & 0xffffu);
            vp[5 * 72] = (ushort_t)(vu.z >> 16);
            vp[6 * 72] = (ushort_t)(vu.w & 0xffffu);
            vp[7 * 72] = (ushort_t)(vu.w >> 16);
        }
        __syncthreads();
        if (k0 + 64 < NQ) kv_load(k0 + 64);

        f32x4 sacc[4] = {{0.f,0.f,0.f,0.f},{0.f,0.f,0.f,0.f},
                         {0.f,0.f,0.f,0.f},{0.f,0.f,0.f,0.f}};
#pragma unroll
        for (int cb = 0; cb < 4; ++cb) {
            short8 kf = *(const short8*)&Ks[it * 2080 + quad * 520 + (cb * 16 + L) * 8];
            sacc[cb] = __builtin_amdgcn_mfma_f32_16x16x32_bf16(kf, qf, sacc[cb], 0, 0, 0);
        }
        if (k0 + 64 > NQ) {
#pragma unroll
            for (int cb = 0; cb < 4; ++cb)
#pragma unroll
                for (int i = 0; i < 4; ++i)
                    if (k0 + cb * 16 + quad * 4 + i >= NQ) sacc[cb][i] = -1e30f;
        }

        float ml = -1e30f;
#pragma unroll
        for (int cb = 0; cb < 4; ++cb)
#pragma unroll
            for (int i = 0; i < 4; ++i) ml = fmaxf(ml, sacc[cb][i]);
        ml = fmaxf(ml, __shfl_xor(ml, 16, 64));
        ml = fmaxf(ml, __shfl_xor(ml, 32, 64));
        float mnew  = fmaxf(mrun, ml);
        float alpha = __expf(mrun - mnew);
        float p[16];
        float rs = 0.f;
#pragma unroll
        for (int cb = 0; cb < 4; ++cb)
#pragma unroll
            for (int i = 0; i < 4; ++i) {
                float e = __expf(sacc[cb][i] - mnew);
                p[cb * 4 + i] = e;
                rs += e;
            }
        rs += __shfl_xor(rs, 16, 64);
        rs += __shfl_xor(rs, 32, 64);
        lrun = lrun * alpha + rs;
        mrun = mnew;

        {
            ushort_t* pw = &Ps[wv * 1152 + L * 72];
#pragma unroll
            for (int cb = 0; cb < 4; ++cb) {
                uint2 u;
                u.x = pack2bf(p[cb * 4 + 0], p[cb * 4 + 1]);
                u.y = pack2bf(p[cb * 4 + 2], p[cb * 4 + 3]);
                *(uint2*)&pw[cb * 16 + quad * 4] = u;
            }
        }
#pragma unroll
        for (int i = 0; i < 4; ++i) {
            float ai = __shfl(alpha, quad * 4 + i, 64);
            oacc[0][i] *= ai;
            oacc[1][i] *= ai;
        }
        __syncthreads();

#pragma unroll
        for (int ks = 0; ks < 2; ++ks) {
            short8 pf = *(const short8*)&Ps[wv * 1152 + L * 72 + ks * 32 + quad * 8];
#pragma unroll
            for (int db = 0; db < 2; ++db) {
                short8 vf = *(const short8*)&Vt[it * 2304 + (db * 16 + L) * 72 + ks * 32 + quad * 8];
                oacc[db] = __builtin_amdgcn_mfma_f32_16x16x32_bf16(pf, vf, oacc[db], 0, 0, 0);
            }
        }
    }

#pragma unroll
    for (int i = 0; i < 4; ++i) {
        float lq = __shfl(lrun, quad * 4 + i, 64);
        float li = 1.f / lq;
        int q = q0 + wv * 16 + quad * 4 + i;
        if (q < NQ) {
            ushort_t* op = attn_out + ((size_t)q * 4 + b) * 256 + h * 32 + L;
            op[0]  = (ushort_t)f2bf1(oacc[0][i] * li);
            op[16] = (ushort_t)f2bf1(oacc[1][i] * li);
        }
    }
}

// ---------------------------------------------------------------------------
// gemm_ln16: fused  C = LN(resid + A@W^T + bias), N = 256, 16 rows/block.
// W staged 256 rows x 64k per phase via gll (8 issues/wave), swizzled read.
// ---------------------------------------------------------------------------
__global__ __launch_bounds__(256) void gemm_ln16(
    const ushort_t* __restrict__ A, const ushort_t* __restrict__ W,
    const float* __restrict__ bias, const float* __restrict__ resid,
    const float* __restrict__ gam, const float* __restrict__ bet,
    float* __restrict__ out, const float* __restrict__ pos,
    ushort_t* __restrict__ out2, int M, int K)
{
    __shared__ ushort_t As[16 * GPAD];    //  2304 B
    __shared__ ushort_t Ws[256 * 64];     // 32768 B linear
    __shared__ float sS[4][16];
    __shared__ float s2S[4][16];

    const int t  = threadIdx.x;
    const int m0 = blockIdx.x * 16;
    const int wv   = t >> 6;
    const int ln   = t & 63;
    const int L    = ln & 15;
    const int quad = ln >> 4;
    const int swz  = (L & 7) << 3;
    const int lrow = ln >> 3;
    const int lchk = (ln & 7) << 3;

    f32x4 acc[4] = {{0.f,0.f,0.f,0.f},{0.f,0.f,0.f,0.f},
                    {0.f,0.f,0.f,0.f},{0.f,0.f,0.f,0.f}};

    for (int k0 = 0; k0 < K; k0 += 64) {
        // stage W: 256 rows x 64 k via gll (8 issues per wave)
#pragma unroll
        for (int j = 0; j < 8; ++j) {
            int r0 = (wv * 8 + j) * 8;
            const ushort_t* g = W + (size_t)(r0 + lrow) * K + k0 + lchk;
            stage_w16(g, &Ws[r0 * 64], ln);
        }
        // stage A: 16 rows x 64 k (threads 0..127, one uint4 each)
        if (t < 128) {
            int r = t >> 3, seg = (t & 7) * 8;
            int m = m0 + r;
            uint4 a = make_uint4(0u, 0u, 0u, 0u);
            if (m < M) a = *(const uint4*)(A + (size_t)m * K + k0 + seg);
            *(uint4*)&As[r * GPAD + seg] = a;
        }
        __syncthreads();
#pragma unroll
        for (int kh = 0; kh < 2; ++kh) {
            short8 af = *(const short8*)&As[L * GPAD + kh * 32 + quad * 8];
#pragma unroll
            for (int cb = 0; cb < 4; ++cb) {
                short8 bf = *(const short8*)&Ws[(wv * 64 + cb * 16 + L) * 64 + ((kh * 32 + quad * 8) ^ swz)];
                acc[cb] = __builtin_amdgcn_mfma_f32_16x16x32_bf16(af, bf, acc[cb], 0, 0, 0);
            }
        }
        __syncthreads();
    }

    // ---- fused LN epilogue ----
    float s[4]  = {0.f, 0.f, 0.f, 0.f};
    float s2[4] = {0.f, 0.f, 0.f, 0.f};
#pragma unroll
    for (int cb = 0; cb < 4; ++cb) {
        int col = wv * 64 + cb * 16 + L;
        float bv = bias[col];
#pragma unroll
        for (int i = 0; i < 4; ++i) {
            int m = m0 + quad * 4 + i;
            float r = (m < M) ? resid[(size_t)m * 256 + col] : 0.f;
            float xv = acc[cb][i] + bv + r;
            acc[cb][i] = xv;
            s[i]  += xv;
            s2[i] += xv * xv;
        }
    }
#pragma unroll
    for (int off = 1; off < 16; off <<= 1) {
#pragma unroll
        for (int i = 0; i < 4; ++i) {
            s[i]  += __shfl_xor(s[i],  off, 64);
            s2[i] += __shfl_xor(s2[i], off, 64);
        }
    }
    if (L == 0) {
#pragma unroll
        for (int i = 0; i < 4; ++i) {
            sS[wv][quad * 4 + i]  = s[i];
            s2S[wv][quad * 4 + i] = s2[i];
        }
    }
    __syncthreads();
    float mean[4], rstd[4];
#pragma unroll
    for (int i = 0; i < 4; ++i) {
        int row = quad * 4 + i;
        float St  = sS[0][row]  + sS[1][row]  + sS[2][row]  + sS[3][row];
        float S2t = s2S[0][row] + s2S[1][row] + s2S[2][row] + s2S[3][row];
        mean[i] = St * (1.f / 256.f);
        float var = S2t * (1.f / 256.f) - mean[i] * mean[i];
        rstd[i] = rsqrtf(var + 1e-5f);
    }
#pragma unroll
    for (int cb = 0; cb < 4; ++cb) {
        int col = wv * 64 + cb * 16 + L;
        float gv = gam[col];
        float bt = bet[col];
#pragma unroll
        for (int i = 0; i < 4; ++i) {
            int m = m0 + quad * 4 + i;
            if (m < M) {
                float y = (acc[cb][i] - mean[i]) * rstd[i] * gv + bt;
                out[(size_t)m * 256 + col] = y;
                if (out2) {
                    float o2 = y + (pos ? pos[(size_t)m * 256 + col] : 0.f);
                    out2[(size_t)m * 256 + col] = (ushort_t)f2bf1(o2);
                }
            }
        }
    }
}

// ---------------------------------------------------------------------------
// Fused offset + attention-weight GEMM (gll W staging).
// ---------------------------------------------------------------------------
__global__ __launch_bounds__(256) void offaw16(
    const ushort_t* __restrict__ A,
    const ushort_t* __restrict__ off_wb, const float* __restrict__ off_b,
    const ushort_t* __restrict__ aw_wb, const float* __restrict__ aw_b,
    float* __restrict__ off_raw, float* __restrict__ aw_raw)
{
    __shared__ ushort_t As[64 * GPAD];
    __shared__ ushort_t Ws[64 * 64];

    const int t  = threadIdx.x;
    const int m0 = blockIdx.x * 64;
    const int by = blockIdx.y;
    const bool isaw = (by >= 4);
    const int n0 = isaw ? (by - 4) * 64 : by * 64;
    const ushort_t* W = isaw ? aw_wb : off_wb;
    const float* bs = isaw ? aw_b : off_b;
    float* C = isaw ? aw_raw : off_raw;
    const int ldc = isaw ? 128 : 256;

    const int trow = t >> 2;
    const int tk   = (t & 3) << 4;
    const int wv   = t >> 6;
    const int ln   = t & 63;
    const int L    = ln & 15;
    const int quad = ln >> 4;
    const int swz  = (L & 7) << 3;
    const int lrow = ln >> 3;
    const int lchk = (ln & 7) << 3;

    const int  mrow = m0 + trow;
    const bool mv   = (mrow < NROW);
    const ushort_t* arow = A + (size_t)mrow * 256 + tk;

    f32x4 acc[4] = {{0.f,0.f,0.f,0.f},{0.f,0.f,0.f,0.f},
                    {0.f,0.f,0.f,0.f},{0.f,0.f,0.f,0.f}};

    for (int k0 = 0; k0 < 256; k0 += 64) {
#pragma unroll
        for (int j = 0; j < 2; ++j) {
            int r0 = (wv * 2 + j) * 8;
            const ushort_t* g = W + (size_t)(n0 + r0 + lrow) * 256 + k0 + lchk;
            stage_w16(g, &Ws[r0 * 64], ln);
        }
        {
            uint4 a0 = make_uint4(0u,0u,0u,0u), a1 = a0;
            if (mv) {
                a0 = *(const uint4*)(arow + k0);
                a1 = *(const uint4*)(arow + k0 + 8);
            }
            *(uint4*)&As[trow * GPAD + tk + 0] = a0;
            *(uint4*)&As[trow * GPAD + tk + 8] = a1;
        }
        __syncthreads();
#pragma unroll
        for (int kh = 0; kh < 2; ++kh) {
            short8 af = *(const short8*)&As[(wv * 16 + L) * GPAD + kh * 32 + quad * 8];
#pragma unroll
            for (int cb = 0; cb < 4; ++cb) {
                short8 bf = *(const short8*)&Ws[(cb * 16 + L) * 64 + ((kh * 32 + quad * 8) ^ swz)];
                acc[cb] = __builtin_amdgcn_mfma_f32_16x16x32_bf16(af, bf, acc[cb], 0, 0, 0);
            }
        }
        __syncthreads();
    }
#pragma unroll
    for (int cb = 0; cb < 4; ++cb) {
        int col = n0 + cb * 16 + L;
        float bv = bs[col];
#pragma unroll
        for (int i = 0; i < 4; ++i) {
            int m = m0 + wv * 16 + quad * 4 + i;
            if (m < NROW)
                C[(size_t)m * ldc + col] = acc[cb][i] + bv;
        }
    }
}

// ---------------------------------------------------------------------------
// Generic A-bf16, W-bf16 -> C-bf16 GEMM (FFN1 with ReLU), gll W staging.
// ---------------------------------------------------------------------------
__global__ __launch_bounds__(256) void gemm16_16(
    const ushort_t* __restrict__ A, const ushort_t* __restrict__ W,
    const float* __restrict__ bias, ushort_t* __restrict__ C,
    int M, int N, int K, int ldc, int relu)
{
    __shared__ ushort_t As[64 * GPAD];
    __shared__ ushort_t Ws[64 * 64];

    const int t  = threadIdx.x;
    const int m0 = blockIdx.x * 64;
    const int n0 = blockIdx.y * 64;
    const int trow = t >> 2;
    const int tk   = (t & 3) << 4;
    const int wv   = t >> 6;
    const int ln   = t & 63;
    const int L    = ln & 15;
    const int quad = ln >> 4;
    const int swz  = (L & 7) << 3;
    const int lrow = ln >> 3;
    const int lchk = (ln & 7) << 3;

    const int  mrow = m0 + trow;
    const bool mv   = (mrow < M);
    const ushort_t* arow = A + (size_t)mrow * K + tk;

    f32x4 acc[4] = {{0.f,0.f,0.f,0.f},{0.f,0.f,0.f,0.f},
                    {0.f,0.f,0.f,0.f},{0.f,0.f,0.f,0.f}};

    for (int k0 = 0; k0 < K; k0 += 64) {
#pragma unroll
        for (int j = 0; j < 2; ++j) {
            int r0 = (wv * 2 + j) * 8;
            const ushort_t* g = W + (size_t)(n0 + r0 + lrow) * K + k0 + lchk;
            stage_w16(g, &Ws[r0 * 64], ln);
        }
        {
            uint4 a0 = make_uint4(0u,0u,0u,0u), a1 = a0;
            if (mv) {
                a0 = *(const uint4*)(arow + k0);
                a1 = *(const uint4*)(arow + k0 + 8);
            }
            *(uint4*)&As[trow * GPAD + tk + 0] = a0;
            *(uint4*)&As[trow * GPAD + tk + 8] = a1;
        }
        __syncthreads();
#pragma unroll
        for (int kh = 0; kh < 2; ++kh) {
            short8 af = *(const short8*)&As[(wv * 16 + L) * GPAD + kh * 32 + quad * 8];
#pragma unroll
            for (int cb = 0; cb < 4; ++cb) {
                short8 bf = *(const short8*)&Ws[(cb * 16 + L) * 64 + ((kh * 32 + quad * 8) ^ swz)];
                acc[cb] = __builtin_amdgcn_mfma_f32_16x16x32_bf16(af, bf, acc[cb], 0, 0, 0);
            }
        }
        __syncthreads();
    }
#pragma unroll
    for (int cb = 0; cb < 4; ++cb) {
        int col = n0 + cb * 16 + L;
        float bv = bias[col];
#pragma unroll
        for (int i = 0; i < 4; ++i) {
            int m = m0 + wv * 16 + quad * 4 + i;
            if (m < M) {
                float o = acc[cb][i] + bv;
                if (relu) o = fmaxf(o, 0.f);
                C[(size_t)m * ldc + col] = (ushort_t)f2bf1(o);
            }
        }
    }
}

// ---------------------------------------------------------------------------
// Multi-scale deformable sampling (unchanged).
// ---------------------------------------------------------------------------
__global__ __launch_bounds__(256) void msdeform16(
    const float* __restrict__ off_raw, const float* __restrict__ aw_raw,
    const float* __restrict__ refp, const ushort_t* __restrict__ value,
    ushort_t* __restrict__ out)
{
    const int row = blockIdx.x;   // q*4+b
    const int b = row & 3;
    const int t = threadIdx.x;

    __shared__ float aw_s[8][17];
    __shared__ float px_s[8][16];
    __shared__ float py_s[8][16];

    const int Hs[4]  = {92, 46, 23, 12};
    const int Wd[4]  = {92, 46, 23, 12};
    const int S0_[4] = {0, 8464, 10580, 11109};

    if (t < 128) {
        int hh = t >> 4, lp = t & 15, l = lp >> 2;
        float ox = off_raw[(size_t)row * 256 + hh * 32 + lp * 2 + 0];
        float oy = off_raw[(size_t)row * 256 + hh * 32 + lp * 2 + 1];
        float rx = refp[((size_t)row * 4 + l) * 2 + 0];
        float ry = refp[((size_t)row * 4 + l) * 2 + 1];
        px_s[hh][lp] = rx * (float)Wd[l] + ox - 0.5f;
        py_s[hh][lp] = ry * (float)Hs[l] + oy - 0.5f;
    }
    if (t < 8) {
        int hh = t;
        float v[16];
        float m = -1e30f;
#pragma unroll
        for (int j = 0; j < 16; ++j) {
            v[j] = aw_raw[(size_t)row * 128 + hh * 16 + j];
            m = fmaxf(m, v[j]);
        }
        float ssum = 0.f;
#pragma unroll
        for (int j = 0; j < 16; ++j) { v[j] = __expf(v[j] - m); ssum += v[j]; }
        float inv = 1.f / ssum;
#pragma unroll
        for (int j = 0; j < 16; ++j) aw_s[hh][j] = v[j] * inv;
    }
    __syncthreads();

    const int h = t >> 5, d = t & 31;
    const ushort_t* vb = value + (size_t)b * 256 + h * 32 + d;
    float acc = 0.f;
#pragma unroll
    for (int l = 0; l < 4; ++l) {
        const int H = Hs[l], W = Wd[l], base = S0_[l];
#pragma unroll
        for (int p = 0; p < 4; ++p) {
            const int lp = l * 4 + p;
            float px = px_s[h][lp], py = py_s[h][lp];
            float x0f = floorf(px), y0f = floorf(py);
            int x0 = (int)x0f, y0 = (int)y0f;
            float wx = px - x0f, wy = py - y0f;
            float sv = 0.f;
#pragma unroll
            for (int dy = 0; dy < 2; ++dy) {
#pragma unroll
                for (int dx = 0; dx < 2; ++dx) {
                    int xi = x0 + dx, yi = y0 + dy;
                    float flag = (xi >= 0 && xi < W && yi >= 0 && yi < H) ? 1.f : 0.f;
                    int xc = xi < 0 ? 0 : (xi >= W ? W - 1 : xi);
                    int yc = yi < 0 ? 0 : (yi >= H ? H - 1 : yi);
                    float wgt = (dx ? wx : 1.f - wx) * (dy ? wy : 1.f - wy);
                    float gv = bf2f(vb[(size_t)(base + yc * W + xc) * 1024]);
                    sv = fmaf(wgt * flag, gv, sv);
                }
            }
            acc = fmaf(aw_s[h][lp], sv, acc);
        }
    }
    out[(size_t)row * 256 + h * 32 + d] = (ushort_t)f2bf1(acc);
}

// ---------------------------------------------------------------------------
extern "C" void kernel_launch(void* const* d_in, const int* in_sizes, int n_in,
                              void* d_out, int out_size, void* d_ws, size_t ws_size,
                              hipStream_t stream)
{
    const float* tgt    = (const float*)d_in[0];
    const float* qpos   = (const float*)d_in[1];
    const float* refp   = (const float*)d_in[2];
    const float* mem    = (const float*)d_in[3];
    const float* in_w   = (const float*)d_in[6];
    const float* in_b   = (const float*)d_in[7];
    const float* outp_w = (const float*)d_in[8];
    const float* outp_b = (const float*)d_in[9];
    const float* off_w  = (const float*)d_in[10];
    const float* off_b  = (const float*)d_in[11];
    const float* aw_w   = (const float*)d_in[12];
    const float* aw_b   = (const float*)d_in[13];
    const float* vp_w   = (const float*)d_in[14];
    const float* vp_b   = (const float*)d_in[15];
    const float* op_w   = (const float*)d_in[16];
    const float* op_b   = (const float*)d_in[17];
    const float* ln1g   = (const float*)d_in[18];
    const float* ln1b   = (const float*)d_in[19];
    const float* ln2g   = (const float*)d_in[20];
    const float* ln2b   = (const float*)d_in[21];
    const float* ln3g   = (const float*)d_in[22];
    const float* ln3b   = (const float*)d_in[23];
    const float* l1w    = (const float*)d_in[24];
    const float* l1b    = (const float*)d_in[25];
    const float* l2w    = (const float*)d_in[26];
    const float* l2b    = (const float*)d_in[27];
    float* out = (float*)d_out;
    float* ws  = (float*)d_ws;

    // workspace layout (float units)
    ushort_t* qkv16    = (ushort_t*)ws;                 // 691200 floats
    ushort_t* att16    = (ushort_t*)(ws + 691200);      // 230400
    float*    tgt_a    = ws + 1843200;                  // 921600
    ushort_t* xca16    = (ushort_t*)(ws + 2764800);     // 230400
    float*    off_raw  = ws + 2995200;                  // 921600
    float*    aw_raw   = ws + 3916800;                  // 460800
    ushort_t* att2_16  = (ushort_t*)(ws + 4377600);     // 230400
    float*    tgt_b    = ws + 4608000;                  // 921600
    ushort_t* tgtb16   = (ushort_t*)(ws + 5529600);     // 230400
    ushort_t* value16  = (ushort_t*)(ws + 5760000);     // 5761536
    ushort_t* hidden16 = (ushort_t*)(ws + 11521536);    // 1843200
    ushort_t* wb       = (ushort_t*)(ws + 13364736);    // 507904 (bf16 weights)

    const ushort_t* in_wb   = wb + WB_IN;
    const ushort_t* vp_wb   = wb + WB_VP;
    const ushort_t* outp_wb = wb + WB_OUTP;
    const ushort_t* off_wb  = wb + WB_OFF;
    const ushort_t* aw_wb   = wb + WB_AW;
    const ushort_t* op_wb   = wb + WB_OP;
    const ushort_t* l1_wb   = wb + WB_L1;
    const ushort_t* l2_wb   = wb + WB_L2;

    dim3 b256(256);

    // 0. one-shot weight conversion fp32 -> bf16 (pre-swizzled)
    hipLaunchKernelGGL(cvt_weights, dim3(496), b256, 0, stream,
                       in_w, vp_w, outp_w, off_w, aw_w, op_w, l1w, l2w, wb);
    // 1. qkv + value projection
    hipLaunchKernelGGL(proj_fused, dim3(1388), b256, 0, stream,
                       tgt, qpos, in_wb, in_b, mem, vp_wb, vp_b, qkv16, value16);
    // 2. flash self-attention
    hipLaunchKernelGGL(sa_flash16, dim3(15, 32), b256, 0, stream, qkv16, att16);
    // 3. out-proj + LN2 fused: tgt_a = LN(tgt + attn@W + b); xca16 = bf16(tgt_a + qpos)
    hipLaunchKernelGGL(gemm_ln16, dim3(225), b256, 0, stream,
                       att16, outp_wb, outp_b, tgt, ln2g, ln2b,
                       tgt_a, qpos, xca16, NROW, 256);
    // 4. fused sampling-offset + attention-weight GEMMs
    hipLaunchKernelGGL(offaw16, dim3(57, 6), b256, 0, stream,
                       xca16, off_wb, off_b, aw_wb, aw_b, off_raw, aw_raw);
    // 5. deformable sampling (bf16 out)
    hipLaunchKernelGGL(msdeform16, dim3(3600), b256, 0, stream,
                       off_raw, aw_raw, refp, value16, att2_16);
    // 6. oproj + LN1 fused: tgt_b = LN(tgt_a + ca@W + b); tgtb16 = bf16(tgt_b)
    hipLaunchKernelGGL(gemm_ln16, dim3(225), b256, 0, stream,
                       att2_16, op_wb, op_b, tgt_a, ln1g, ln1b,
                       tgt_b, (const float*)nullptr, tgtb16, NROW, 256);
    // 7. FFN1 + ReLU (bf16 out)
    hipLaunchKernelGGL(gemm16_16, dim3(57, 16), b256, 0, stream,
                       tgtb16, l1_wb, l1b, hidden16, NROW, 1024, 256, 1024, 1);
    // 8. FFN2 + LN3 fused -> d_out
    hipLaunchKernelGGL(gemm_ln16, dim3(225), b256, 0, stream,
                       hidden16, l2_wb, l2b, tgt_b, ln3g, ln3b,
                       out, (const float*)nullptr, (ushort_t*)nullptr, NROW, 1024);
}